// Round 12
// baseline (430.218 us; speedup 1.0000x reference)
//
#include <hip/hip_runtime.h>
#include <stdint.h>

// ---------------------------------------------------------------------------
// R19: R14 champion (358.6 us) + ONE isolated change: hoisted MFMA in
// midB/midC (moved from after the B1-B3 prologue to before B1). R10 proved
// the hoist is spill-free at (256,4) (VGPR 64, clean traffic); its +16 us
// there was the 3-phase bounce cycling, which R14/R19 do not have. Mechanism:
// W16 L2 loads + 24 MFMAs overlap the prologue's global-load latency chain;
// af regs die early, acc lives through the low-pressure fold (~10 regs).
// Everything else R14-byte-identical. Revert trigger: FETCH/WRITE inflation
// (spills) or flat duration.
// R18 post-mortem: 2-chunks-per-block dead (3rd spill failure; WRITE 2x).
// ---------------------------------------------------------------------------

#define BB 4
#define SP 65536
#define SS 196608
#define CI 1024                 // 64-px chunks per batch
#define NG 16                   // groups per batch (64 chunks each)
#define INVN (1.0f / 196608.0f)

typedef __attribute__((ext_vector_type(8))) _Float16 half8;
typedef __attribute__((ext_vector_type(4))) float    f32x4;

// ---------------- prep: histograms + weight prep + Ggrp zero ----------------
__global__ __launch_bounds__(256)
void prep(const int* __restrict__ ex, const float* __restrict__ W0,
          const float* __restrict__ b0, const float* __restrict__ Wr,
          const float* __restrict__ Wfin,
          _Float16* __restrict__ Wt16, _Float16* __restrict__ Wf16p,
          float* __restrict__ Wf32, float* __restrict__ tab32,
          int* __restrict__ Hsub, int* __restrict__ Hqrt,
          float* __restrict__ Gz)
{
    __shared__ int hist[16][24];
    int tid = threadIdx.x, bi = blockIdx.x;        // 256 blocks
    int b = bi >> 6, g = (bi >> 2) & 15, q = bi & 3;  // quarter-group = 16 chunks
    for (int i = tid; i < 384; i += 256) hist[i / 24][i % 24] = 0;
    __syncthreads();
    for (int it = 0; it < 4; ++it) {
        int pl = it * 256 + tid;                   // 0..1023 within quarter
        const int* ep = ex + ((size_t)b * SP + g * 4096 + q * 1024 + pl) * 3;
        int j = pl >> 6;                           // chunk within quarter
        atomicAdd(&hist[j][ep[0]], 1);
        atomicAdd(&hist[j][8 + ep[1]], 1);
        atomicAdd(&hist[j][16 + ep[2]], 1);
    }
    __syncthreads();
    for (int i = tid; i < 384; i += 256) {
        int j = i / 24, cv = i % 24;
        Hsub[(size_t)(b * CI + g * 64 + q * 16 + j) * 24 + cv] = hist[j][cv];
    }
    if (tid < 24) {
        int s = 0;
        for (int j = 0; j < 16; ++j) s += hist[j][tid];
        Hqrt[((size_t)(b * NG + g) * 4 + q) * 24 + tid] = s;   // non-atomic
    }
    {   // weight prep + Ggrp zeroing (all 256 blocks share)
        int i0 = bi * 256 + tid, nth = 256 * 256;
        for (int idx = i0; idx < 12288; idx += nth)     // Ggrp1..3 zero
            Gz[idx] = 0.f;
        for (int idx = i0; idx < 36864; idx += nth) {   // Wt16[l][c][f][d]
            int d = idx & 63, f = (idx >> 6) & 63, lc = idx >> 12;
            Wt16[idx] = (_Float16)Wr[(size_t)(lc * 64 + d) * 64 + f];
        }
        for (int idx = i0; idx < 3072; idx += nth) {    // Wf16p[c][n16][d]
            int d = idx & 63, n = (idx >> 6) & 15, c = idx >> 10;
            Wf16p[idx] = (n < 8) ? (_Float16)Wfin[(size_t)(c * 64 + d) * 8 + n]
                                 : (_Float16)0.f;
        }
        for (int idx = i0; idx < 1536; idx += nth) {    // Wf32[ck][d]
            int d = idx & 63, ck = idx >> 6;
            Wf32[idx] = Wfin[(size_t)((ck >> 3) * 64 + d) * 8 + (ck & 7)];
        }
        for (int idx = i0; idx < 1536; idx += nth) {    // tab32[cv][f]
            int f = idx & 63, v = (idx >> 6) & 7, c = idx >> 9;
            float xv = v * 0.25f - 1.0f;
            tab32[idx] = fmaxf(W0[c * 64 + f] * xv + b0[c * 64 + f], 0.f);
        }
    }
}

// ---------------- midA: R7-exact layer0 (LUT, hist carry) + dense1 -> Y -----
__global__ __launch_bounds__(256, 4)
void midA(const int* __restrict__ ex,
          const int* __restrict__ Hsub, const int* __restrict__ Hqrt,
          const float* __restrict__ tab32,
          const _Float16* __restrict__ W16, const float* __restrict__ Wd32,
          const float* __restrict__ bias, _Float16* __restrict__ Y,
          float* __restrict__ A64, float* __restrict__ Ggrp)
{
    __shared__ float stab[1536];
    __shared__ __align__(16) _Float16 bounce3[3][64 * 72];
    __shared__ float segwt[3][4][64];
    __shared__ float basearr[192];
    __shared__ float hpart[4][24];
    __shared__ float carry[64];

    int tid = threadIdx.x, bi = blockIdx.x;
    int b = bi >> 10, ci = bi & 1023, g = ci >> 6, cr = ci & 63;
    int w = tid >> 6, ln = tid & 63, lm = ln & 15, lq = ln >> 4;
    int P0 = ci * 64;

    for (int i = tid; i < 1536; i += 256) stab[i] = tab32[i];
    if (ln < 24) {                             // distributed hist prefix
        float s = 0.f;
        for (int j = w; j < g; j += 4) {
            const int* hq = Hqrt + ((size_t)(b * NG + j) * 4) * 24 + ln;
            s += (float)(hq[0] + hq[24] + hq[48] + hq[72]);
        }
        const int* hp = Hsub + (size_t)(b * CI + g * 64) * 24 + ln;
        for (int j = w; j < cr; j += 4) s += (float)hp[j * 24];
        hpart[w][ln] = s;
    }
    __syncthreads();                           // B1: stab + hpart

    // layer-0 local values: thread (f=ln, seg=w) scans 16 px
    float y0[3][16];
    {
#pragma unroll
        for (int p = 0; p < 16; ++p) {
            const int* ep = ex + ((size_t)b * SP + P0 + w * 16 + p) * 3;
            y0[0][p] = stab[ep[0] * 64 + ln];
            y0[1][p] = stab[(8 + ep[1]) * 64 + ln];
            y0[2][p] = stab[(16 + ep[2]) * 64 + ln];
        }
#pragma unroll
        for (int c = 0; c < 3; ++c)
#pragma unroll
            for (int p = 1; p < 16; ++p) y0[c][p] += y0[c][p - 1];
#pragma unroll
        for (int c = 0; c < 3; ++c) segwt[c][w][ln] = y0[c][15];
    }
    if (tid < 64) {                            // layer-0 carry from hist
        float c0 = 0.f;
#pragma unroll
        for (int cv = 0; cv < 24; ++cv) {
            float cnt = hpart[0][cv] + hpart[1][cv] + hpart[2][cv] + hpart[3][cv];
            c0 += cnt * stab[cv * 64 + tid];
        }
        carry[tid] = c0;
    }
    __syncthreads();                           // B2: segwt + carry

    {   // combine channels -> bounce (layer-0 chunk-local flattened cumsum)
        float off0[3];
#pragma unroll
        for (int c = 0; c < 3; ++c) {
            float o = 0.f;
            for (int w2 = 0; w2 < w; ++w2) o += segwt[c][w2][ln];
            off0[c] = o;
        }
#pragma unroll
        for (int p = 0; p < 16; ++p) {
            float S0 = y0[0][p] + off0[0], S1 = y0[1][p] + off0[1], S2 = y0[2][p] + off0[2];
            float P1 = p ? y0[1][p - 1] + off0[1] : off0[1];
            float P2 = p ? y0[2][p - 1] + off0[2] : off0[2];
            int row = w * 16 + p;
            bounce3[0][row * 72 + ln] = (_Float16)(S0 + P1 + P2);
            bounce3[1][row * 72 + ln] = (_Float16)(S0 + S1 + P2);
            bounce3[2][row * 72 + ln] = (_Float16)(S0 + S1 + S2);
        }
    }
    if (tid < 192) {                           // basefold for dense1
        int c = tid >> 6, f = tid & 63;
        const float* wp = Wd32 + (size_t)(c * 64) * 64 + f;
        float a = 0.f;
        for (int d = 0; d < 64; ++d) a += carry[d] * wp[d * 64];
        basearr[tid] = bias[tid] + INVN * a;
    }
    __syncthreads();                           // B3: bounce + basearr

    // dense1 MFMA
    f32x4 acc[3][4];
#pragma unroll
    for (int c = 0; c < 3; ++c) {
        const half8* bb = (const half8*)&bounce3[c][0];
        half8 a0 = bb[(w * 16 + lm) * 9 + lq];
        half8 a1 = bb[(w * 16 + lm) * 9 + 4 + lq];
#pragma unroll
        for (int nt = 0; nt < 4; ++nt) {
            const half8* bp = (const half8*)(W16 + (size_t)(c * 64 + nt * 16 + lm) * 64);
            f32x4 t = {0.f, 0.f, 0.f, 0.f};
            t = __builtin_amdgcn_mfma_f32_16x16x32_f16(a0, bp[lq],     t, 0, 0, 0);
            t = __builtin_amdgcn_mfma_f32_16x16x32_f16(a1, bp[4 + lq], t, 0, 0, 0);
            acc[c][nt] = t;
        }
    }

    // relu + scan + shuffle
    float s[3][4][4], wexcl[3][4];
#pragma unroll
    for (int c = 0; c < 3; ++c)
#pragma unroll
        for (int nt = 0; nt < 4; ++nt) {
            float base = basearr[c * 64 + nt * 16 + lm];
            float run = 0.f;
#pragma unroll
            for (int r = 0; r < 4; ++r) {
                float yv = fmaxf(base + INVN * acc[c][nt][r], 0.f);
                run += yv; s[c][nt][r] = run;
            }
            float v = run;
            float t1 = __shfl_up(v, 16); if (lq >= 1) v += t1;
            float t2 = __shfl_up(v, 32); if (lq >= 2) v += t2;
            wexcl[c][nt] = v - run;
            if (lq == 3) segwt[c][w][nt * 16 + lm] = v;   // wave totals
        }
    __syncthreads();                           // B4: wave tops

    {
        float off[3][4], tot[3][4];
#pragma unroll
        for (int c = 0; c < 3; ++c)
#pragma unroll
            for (int nt = 0; nt < 4; ++nt) {
                float o = wexcl[c][nt], ts = 0.f;
#pragma unroll
                for (int w2 = 0; w2 < 4; ++w2) {
                    float wv = segwt[c][w2][nt * 16 + lm];
                    ts += wv;
                    if (w2 < w) o += wv;
                }
                off[c][nt] = o; tot[c][nt] = ts;
            }
        if (w == 0 && lq == 0)
#pragma unroll
            for (int nt = 0; nt < 4; ++nt) {
                float t3 = tot[0][nt] + tot[1][nt] + tot[2][nt];
                A64[(size_t)(b * CI + ci) * 64 + nt * 16 + lm] = t3;
                atomicAdd(&Ggrp[(size_t)(b * NG + g) * 64 + nt * 16 + lm], t3);
            }
#pragma unroll
        for (int nt = 0; nt < 4; ++nt)
#pragma unroll
            for (int r = 0; r < 4; ++r) {
                float S0 = off[0][nt] + s[0][nt][r];
                float S1 = off[1][nt] + s[1][nt][r];
                float S2 = off[2][nt] + s[2][nt][r];
                float P1 = off[1][nt] + (r ? s[1][nt][r - 1] : 0.f);
                float P2 = off[2][nt] + (r ? s[2][nt][r - 1] : 0.f);
                int row = w * 16 + lq * 4 + r;
                bounce3[0][row * 72 + nt * 16 + lm] = (_Float16)(S0 + P1 + P2);
                bounce3[1][row * 72 + nt * 16 + lm] = (_Float16)(S0 + S1 + P2);
                bounce3[2][row * 72 + nt * 16 + lm] = (_Float16)(S0 + S1 + S2);
            }
    }
    __syncthreads();                           // B5: store staging
#pragma unroll
    for (int q = 0; q < 6; ++q) {
        int idx = q * 256 + tid;
        int c = idx >> 9, rem = idx & 511;
        int pix = rem >> 3, f8 = rem & 7;
        half8 v = *(const half8*)&bounce3[c][pix * 72 + f8 * 8];
        ((half8*)(Y + ((size_t)(b * 3 + c) * SP + P0 + pix) * 64))[f8] = v;
    }
}

// ---------------- midB: dense2, Y in-place (R14 + hoisted MFMA) -------------
__global__ __launch_bounds__(256, 4)
void midB(const _Float16* Yin, _Float16* Yout,
          const float* __restrict__ A64p, const float* __restrict__ Ggrp_p,
          const _Float16* __restrict__ W16, const float* __restrict__ Wd32,
          const float* __restrict__ bias,
          float* __restrict__ A64, float* __restrict__ Ggrp)
{
    __shared__ __align__(16) _Float16 bounce3[3][64 * 72];
    __shared__ float wtop[3][4][64];
    __shared__ float basearr[192];
    __shared__ float cpart[4][64];
    __shared__ float carry[64];

    int tid = threadIdx.x, bi = blockIdx.x;
    int b = bi >> 10, ci = bi & 1023, g = ci >> 6, cr = ci & 63;
    int w = tid >> 6, ln = tid & 63, lm = ln & 15, lq = ln >> 4;
    int P0 = ci * 64;

    // A-frags first
    half8 af0[3], af1[3];
#pragma unroll
    for (int c = 0; c < 3; ++c) {
        const half8* ap = (const half8*)(Yin + ((size_t)(b * 3 + c) * SP + P0 + w * 16 + lm) * 64);
        af0[c] = ap[lq]; af1[c] = ap[4 + lq];
    }
    {   // distributed carry prefix
        float s = 0.f;
        for (int j = w; j < g; j += 4)
            s += Ggrp_p[(size_t)(b * NG + j) * 64 + ln];
        const float* ap = A64p + (size_t)(b * CI + g * 64) * 64 + ln;
        for (int j = w; j < cr; j += 4) s += ap[j * 64];
        cpart[w][ln] = s;
    }

    // HOISTED dense2 MFMA (depends only on af + W16; overlaps prologue chain)
    f32x4 acc[3][4];
#pragma unroll
    for (int c = 0; c < 3; ++c)
#pragma unroll
        for (int nt = 0; nt < 4; ++nt) {
            const half8* bp = (const half8*)(W16 + (size_t)(c * 64 + nt * 16 + lm) * 64);
            f32x4 t = {0.f, 0.f, 0.f, 0.f};
            t = __builtin_amdgcn_mfma_f32_16x16x32_f16(af0[c], bp[lq],     t, 0, 0, 0);
            t = __builtin_amdgcn_mfma_f32_16x16x32_f16(af1[c], bp[4 + lq], t, 0, 0, 0);
            acc[c][nt] = t;
        }
    __syncthreads();                           // B1
    if (tid < 64)
        carry[tid] = cpart[0][tid] + cpart[1][tid] + cpart[2][tid] + cpart[3][tid];
    __syncthreads();                           // B2
    if (tid < 192) {
        int c = tid >> 6, f = tid & 63;
        const float* wp = Wd32 + (size_t)(c * 64) * 64 + f;
        float a = 0.f;
        for (int d = 0; d < 64; ++d) a += carry[d] * wp[d * 64];
        basearr[tid] = bias[tid] + INVN * a;
    }
    __syncthreads();                           // B3

    float s[3][4][4], wexcl[3][4];
#pragma unroll
    for (int c = 0; c < 3; ++c)
#pragma unroll
        for (int nt = 0; nt < 4; ++nt) {
            float base = basearr[c * 64 + nt * 16 + lm];
            float run = 0.f;
#pragma unroll
            for (int r = 0; r < 4; ++r) {
                float yv = fmaxf(base + INVN * acc[c][nt][r], 0.f);
                run += yv; s[c][nt][r] = run;
            }
            float v = run;
            float t1 = __shfl_up(v, 16); if (lq >= 1) v += t1;
            float t2 = __shfl_up(v, 32); if (lq >= 2) v += t2;
            wexcl[c][nt] = v - run;
            if (lq == 3) wtop[c][w][nt * 16 + lm] = v;
        }
    __syncthreads();                           // B4

    {
        float off[3][4], tot[3][4];
#pragma unroll
        for (int c = 0; c < 3; ++c)
#pragma unroll
            for (int nt = 0; nt < 4; ++nt) {
                float o = wexcl[c][nt], ts = 0.f;
#pragma unroll
                for (int w2 = 0; w2 < 4; ++w2) {
                    float wv = wtop[c][w2][nt * 16 + lm];
                    ts += wv;
                    if (w2 < w) o += wv;
                }
                off[c][nt] = o; tot[c][nt] = ts;
            }
        if (w == 0 && lq == 0)
#pragma unroll
            for (int nt = 0; nt < 4; ++nt) {
                float t3 = tot[0][nt] + tot[1][nt] + tot[2][nt];
                A64[(size_t)(b * CI + ci) * 64 + nt * 16 + lm] = t3;
                atomicAdd(&Ggrp[(size_t)(b * NG + g) * 64 + nt * 16 + lm], t3);
            }
#pragma unroll
        for (int nt = 0; nt < 4; ++nt)
#pragma unroll
            for (int r = 0; r < 4; ++r) {
                float S0 = off[0][nt] + s[0][nt][r];
                float S1 = off[1][nt] + s[1][nt][r];
                float S2 = off[2][nt] + s[2][nt][r];
                float P1 = off[1][nt] + (r ? s[1][nt][r - 1] : 0.f);
                float P2 = off[2][nt] + (r ? s[2][nt][r - 1] : 0.f);
                int row = w * 16 + lq * 4 + r;
                bounce3[0][row * 72 + nt * 16 + lm] = (_Float16)(S0 + P1 + P2);
                bounce3[1][row * 72 + nt * 16 + lm] = (_Float16)(S0 + S1 + P2);
                bounce3[2][row * 72 + nt * 16 + lm] = (_Float16)(S0 + S1 + S2);
            }
    }
    __syncthreads();                           // B5
#pragma unroll
    for (int q = 0; q < 6; ++q) {
        int idx = q * 256 + tid;
        int c = idx >> 9, rem = idx & 511;
        int pix = rem >> 3, f8 = rem & 7;
        half8 v = *(const half8*)&bounce3[c][pix * 72 + f8 * 8];
        ((half8*)(Yout + ((size_t)(b * 3 + c) * SP + P0 + pix) * 64))[f8] = v;
    }
}

// ---------------- midC: dense3 + final MFMA -> out (R14 + hoisted MFMA) -----
__global__ __launch_bounds__(256, 4)
void midC(const _Float16* __restrict__ Yin,
          const float* __restrict__ A64p, const float* __restrict__ Ggrp_p,
          const _Float16* __restrict__ W16, const float* __restrict__ Wd32,
          const float* __restrict__ bias,
          const _Float16* __restrict__ Wf16p, const float* __restrict__ bfin,
          float* __restrict__ out, float* __restrict__ A64, float* __restrict__ Ggrp)
{
    __shared__ __align__(16) _Float16 bounce3[3][64 * 72];
    __shared__ float wtop[3][4][64];
    __shared__ float basearr[192];
    __shared__ float cpart[4][64];
    __shared__ float carry[64];
    __shared__ __align__(16) float outst[64 * 28];

    int tid = threadIdx.x, bi = blockIdx.x;
    int b = bi >> 10, ci = bi & 1023, g = ci >> 6, cr = ci & 63;
    int w = tid >> 6, ln = tid & 63, lm = ln & 15, lq = ln >> 4;
    int P0 = ci * 64;

    half8 af0[3], af1[3];
#pragma unroll
    for (int c = 0; c < 3; ++c) {
        const half8* ap = (const half8*)(Yin + ((size_t)(b * 3 + c) * SP + P0 + w * 16 + lm) * 64);
        af0[c] = ap[lq]; af1[c] = ap[4 + lq];
    }
    {
        float s = 0.f;
        for (int j = w; j < g; j += 4)
            s += Ggrp_p[(size_t)(b * NG + j) * 64 + ln];
        const float* ap = A64p + (size_t)(b * CI + g * 64) * 64 + ln;
        for (int j = w; j < cr; j += 4) s += ap[j * 64];
        cpart[w][ln] = s;
    }

    // HOISTED dense3 MFMA
    f32x4 acc[3][4];
#pragma unroll
    for (int c = 0; c < 3; ++c)
#pragma unroll
        for (int nt = 0; nt < 4; ++nt) {
            const half8* bp = (const half8*)(W16 + (size_t)(c * 64 + nt * 16 + lm) * 64);
            f32x4 t = {0.f, 0.f, 0.f, 0.f};
            t = __builtin_amdgcn_mfma_f32_16x16x32_f16(af0[c], bp[lq],     t, 0, 0, 0);
            t = __builtin_amdgcn_mfma_f32_16x16x32_f16(af1[c], bp[4 + lq], t, 0, 0, 0);
            acc[c][nt] = t;
        }
    __syncthreads();                           // B1
    if (tid < 64)
        carry[tid] = cpart[0][tid] + cpart[1][tid] + cpart[2][tid] + cpart[3][tid];
    __syncthreads();                           // B2
    if (tid < 192) {
        int c = tid >> 6, f = tid & 63;
        const float* wp = Wd32 + (size_t)(c * 64) * 64 + f;
        float a = 0.f;
        for (int d = 0; d < 64; ++d) a += carry[d] * wp[d * 64];
        basearr[tid] = bias[tid] + INVN * a;
    }
    __syncthreads();                           // B3

    float s[3][4][4], wexcl[3][4];
#pragma unroll
    for (int c = 0; c < 3; ++c)
#pragma unroll
        for (int nt = 0; nt < 4; ++nt) {
            float base = basearr[c * 64 + nt * 16 + lm];
            float run = 0.f;
#pragma unroll
            for (int r = 0; r < 4; ++r) {
                float yv = fmaxf(base + INVN * acc[c][nt][r], 0.f);
                run += yv; s[c][nt][r] = run;
            }
            float v = run;
            float t1 = __shfl_up(v, 16); if (lq >= 1) v += t1;
            float t2 = __shfl_up(v, 32); if (lq >= 2) v += t2;
            wexcl[c][nt] = v - run;
            if (lq == 3) wtop[c][w][nt * 16 + lm] = v;
        }
    __syncthreads();                           // B4

    {
        float off[3][4], tot[3][4];
#pragma unroll
        for (int c = 0; c < 3; ++c)
#pragma unroll
            for (int nt = 0; nt < 4; ++nt) {
                float o = wexcl[c][nt], ts = 0.f;
#pragma unroll
                for (int w2 = 0; w2 < 4; ++w2) {
                    float wv = wtop[c][w2][nt * 16 + lm];
                    ts += wv;
                    if (w2 < w) o += wv;
                }
                off[c][nt] = o; tot[c][nt] = ts;
            }
        if (w == 0 && lq == 0)
#pragma unroll
            for (int nt = 0; nt < 4; ++nt) {
                float t3 = tot[0][nt] + tot[1][nt] + tot[2][nt];
                A64[(size_t)(b * CI + ci) * 64 + nt * 16 + lm] = t3;
                atomicAdd(&Ggrp[(size_t)(b * NG + g) * 64 + nt * 16 + lm], t3);
            }
#pragma unroll
        for (int nt = 0; nt < 4; ++nt)
#pragma unroll
            for (int r = 0; r < 4; ++r) {
                float S0 = off[0][nt] + s[0][nt][r];
                float S1 = off[1][nt] + s[1][nt][r];
                float S2 = off[2][nt] + s[2][nt][r];
                float P1 = off[1][nt] + (r ? s[1][nt][r - 1] : 0.f);
                float P2 = off[2][nt] + (r ? s[2][nt][r - 1] : 0.f);
                int row = w * 16 + lq * 4 + r;
                bounce3[0][row * 72 + nt * 16 + lm] = (_Float16)(S0 + P1 + P2);
                bounce3[1][row * 72 + nt * 16 + lm] = (_Float16)(S0 + S1 + P2);
                bounce3[2][row * 72 + nt * 16 + lm] = (_Float16)(S0 + S1 + S2);
            }
    }
    __syncthreads();                           // B5: layer-3 local staged

    // final dense via padded-Wf MFMA (n=16: 8 logits + 8 zero)
#pragma unroll
    for (int c = 0; c < 3; ++c) {
        const half8* bb = (const half8*)&bounce3[c][0];
        half8 fa0 = bb[(w * 16 + lm) * 9 + lq];
        half8 fa1 = bb[(w * 16 + lm) * 9 + 4 + lq];
        const half8* fb = (const half8*)(Wf16p + (size_t)(c * 16 + lm) * 64);
        f32x4 t = {0.f, 0.f, 0.f, 0.f};
        t = __builtin_amdgcn_mfma_f32_16x16x32_f16(fa0, fb[lq],     t, 0, 0, 0);
        t = __builtin_amdgcn_mfma_f32_16x16x32_f16(fa1, fb[4 + lq], t, 0, 0, 0);
        if (lm < 8) {
            float bz = bfin[c * 8 + lm];
#pragma unroll
            for (int r = 0; r < 4; ++r)
                outst[(w * 16 + lq * 4 + r) * 28 + c * 8 + lm] = bz + INVN * t[r];
        }
    }
    __syncthreads();                           // B6
    {   // 64 px x 24 floats = 384 float4
        float4* obase = (float4*)(out + ((size_t)b * SS + (size_t)P0 * 3) * 8);
#pragma unroll
        for (int k = 0; k < 2; ++k) {
            int idx = k * 256 + tid;
            if (idx < 384) {
                int pix = idx / 6, sub = (idx % 6) * 4;
                obase[idx] = *(const float4*)&outst[pix * 28 + sub];
            }
        }
    }
}

// ---------------- fixk: out += INVN * Wf . carry3 (distributed dot) ---------
__global__ __launch_bounds__(256, 4)
void fixk(const float* __restrict__ A64p, const float* __restrict__ Ggrp_p,
          const float* __restrict__ Wf32, float* __restrict__ out)
{
    __shared__ float cpart[4][64];
    __shared__ float carry[64];
    __shared__ float part[24][8];
    __shared__ float vfix[24];
    int tid = threadIdx.x, bi = blockIdx.x;
    int b = bi >> 10, ci = bi & 1023, g = ci >> 6, cr = ci & 63;
    int w = tid >> 6, ln = tid & 63;
    int P0 = ci * 64;

    {
        float s = 0.f;
        for (int j = w; j < g; j += 4)
            s += Ggrp_p[(size_t)(b * NG + j) * 64 + ln];
        const float* ap = A64p + (size_t)(b * CI + g * 64) * 64 + ln;
        for (int j = w; j < cr; j += 4) s += ap[j * 64];
        cpart[w][ln] = s;
    }
    __syncthreads();
    if (tid < 64)
        carry[tid] = cpart[0][tid] + cpart[1][tid] + cpart[2][tid] + cpart[3][tid];
    __syncthreads();
    if (tid < 192) {                           // 24 outputs x 8 segments
        int ck = tid >> 3, sg = tid & 7;
        const float* wp = Wf32 + ck * 64 + sg * 8;
        const float* cp = carry + sg * 8;
        float vf = 0.f;
#pragma unroll
        for (int d = 0; d < 8; ++d) vf += cp[d] * wp[d];
        part[ck][sg] = vf;
    }
    __syncthreads();
    if (tid < 24) {
        float vf = 0.f;
#pragma unroll
        for (int j = 0; j < 8; ++j) vf += part[tid][j];
        vfix[tid] = INVN * vf;
    }
    __syncthreads();
    float4* obase = (float4*)(out + ((size_t)b * SS + (size_t)P0 * 3) * 8);
#pragma unroll
    for (int k = 0; k < 2; ++k) {
        int idx = k * 256 + tid;
        if (idx < 384) {
            int sub = (idx % 6) * 4;
            float4 v = obase[idx];
            v.x += vfix[sub];
            v.y += vfix[sub + 1];
            v.z += vfix[sub + 2];
            v.w += vfix[sub + 3];
            obase[idx] = v;
        }
    }
}

// ---------------- host -------------------------------------------------------
extern "C" void kernel_launch(void* const* d_in, const int* in_sizes, int n_in,
                              void* d_out, int out_size, void* d_ws, size_t ws_size,
                              hipStream_t stream)
{
    const int*   ex   = (const int*)d_in[0];
    const float* W0   = (const float*)d_in[1];
    const float* b0   = (const float*)d_in[2];
    const float* Wr   = (const float*)d_in[3];
    const float* br   = (const float*)d_in[4];
    const float* Wfin = (const float*)d_in[5];
    const float* bfin = (const float*)d_in[6];
    float* out = (float*)d_out;

    char* ws = (char*)d_ws;
    size_t off = 0;
    _Float16* Y = (_Float16*)(ws + off); off += (size_t)BB * 3 * SP * 64 * 2;  // 100.7 MB
    float* Ggrp1 = (float*)(ws + off); off += (size_t)BB * NG * 64 * 4;        // contiguous
    float* Ggrp2 = (float*)(ws + off); off += (size_t)BB * NG * 64 * 4;
    float* Ggrp3 = (float*)(ws + off); off += (size_t)BB * NG * 64 * 4;
    float* A64_1 = (float*)(ws + off); off += (size_t)BB * CI * 64 * 4;
    float* A64_2 = (float*)(ws + off); off += (size_t)BB * CI * 64 * 4;
    float* A64_3 = (float*)(ws + off); off += (size_t)BB * CI * 64 * 4;
    int* Hsub = (int*)(ws + off); off += (size_t)BB * CI * 24 * 4;
    int* Hqrt = (int*)(ws + off); off += (size_t)BB * NG * 4 * 24 * 4;
    _Float16* Wt16  = (_Float16*)(ws + off); off += 36864 * 2;
    _Float16* Wf16p = (_Float16*)(ws + off); off += 3072 * 2;
    float* Wf32  = (float*)(ws + off); off += 1536 * 4;
    float* tab32 = (float*)(ws + off); off += 1536 * 4;

    prep<<<256, 256, 0, stream>>>(ex, W0, b0, Wr, Wfin,
                                  Wt16, Wf16p, Wf32, tab32,
                                  Hsub, Hqrt, Ggrp1);
    midA<<<4096, 256, 0, stream>>>(ex, Hsub, Hqrt, tab32,
                                   Wt16, Wr, br, Y, A64_1, Ggrp1);
    midB<<<4096, 256, 0, stream>>>(Y, Y, A64_1, Ggrp1,
                                   Wt16 + 12288, Wr + 12288, br + 192,
                                   A64_2, Ggrp2);
    midC<<<4096, 256, 0, stream>>>(Y, A64_2, Ggrp2,
                                   Wt16 + 24576, Wr + 24576, br + 384,
                                   Wf16p, bfin, out, A64_3, Ggrp3);
    fixk<<<4096, 256, 0, stream>>>(A64_3, Ggrp3, Wf32, out);
}

// Round 13
// 355.011 us; speedup vs baseline: 1.2118x; 1.2118x over previous
//
#include <hip/hip_runtime.h>
#include <stdint.h>

// ---------------------------------------------------------------------------
// R20: R14 champion (358.6 us) + ONE isolated change: fixk processes 4
// consecutive chunks per block (4096 -> 1024 blocks, all co-resident).
// R19 post-mortem: hoisted MFMA reverted (+30 us/mid — R14's ordering drains
// af latency during barrier waits for free; hoisting serialized it pre-B1).
// fixk was the last unprofiled ~40 us: full carry prologue replicated per
// chunk. Unlike the mids, fixk has NO MFMA/AGPR pressure -> the 4-chunk
// amortization that spilled in mids (R17/R18) is spill-safe here: prologue
// once per quad, carry4 via 3 coalesced row-adds, 4 dots on one Wf stream,
// 1536 coalesced float4 RMW. Everything else R14-byte-identical.
// ---------------------------------------------------------------------------

#define BB 4
#define SP 65536
#define SS 196608
#define CI 1024                 // 64-px chunks per batch
#define NG 16                   // groups per batch (64 chunks each)
#define INVN (1.0f / 196608.0f)

typedef __attribute__((ext_vector_type(8))) _Float16 half8;
typedef __attribute__((ext_vector_type(4))) float    f32x4;

// ---------------- prep: histograms + weight prep + Ggrp zero ----------------
__global__ __launch_bounds__(256)
void prep(const int* __restrict__ ex, const float* __restrict__ W0,
          const float* __restrict__ b0, const float* __restrict__ Wr,
          const float* __restrict__ Wfin,
          _Float16* __restrict__ Wt16, _Float16* __restrict__ Wf16p,
          float* __restrict__ Wf32, float* __restrict__ tab32,
          int* __restrict__ Hsub, int* __restrict__ Hqrt,
          float* __restrict__ Gz)
{
    __shared__ int hist[16][24];
    int tid = threadIdx.x, bi = blockIdx.x;        // 256 blocks
    int b = bi >> 6, g = (bi >> 2) & 15, q = bi & 3;  // quarter-group = 16 chunks
    for (int i = tid; i < 384; i += 256) hist[i / 24][i % 24] = 0;
    __syncthreads();
    for (int it = 0; it < 4; ++it) {
        int pl = it * 256 + tid;                   // 0..1023 within quarter
        const int* ep = ex + ((size_t)b * SP + g * 4096 + q * 1024 + pl) * 3;
        int j = pl >> 6;                           // chunk within quarter
        atomicAdd(&hist[j][ep[0]], 1);
        atomicAdd(&hist[j][8 + ep[1]], 1);
        atomicAdd(&hist[j][16 + ep[2]], 1);
    }
    __syncthreads();
    for (int i = tid; i < 384; i += 256) {
        int j = i / 24, cv = i % 24;
        Hsub[(size_t)(b * CI + g * 64 + q * 16 + j) * 24 + cv] = hist[j][cv];
    }
    if (tid < 24) {
        int s = 0;
        for (int j = 0; j < 16; ++j) s += hist[j][tid];
        Hqrt[((size_t)(b * NG + g) * 4 + q) * 24 + tid] = s;   // non-atomic
    }
    {   // weight prep + Ggrp zeroing (all 256 blocks share)
        int i0 = bi * 256 + tid, nth = 256 * 256;
        for (int idx = i0; idx < 12288; idx += nth)     // Ggrp1..3 zero
            Gz[idx] = 0.f;
        for (int idx = i0; idx < 36864; idx += nth) {   // Wt16[l][c][f][d]
            int d = idx & 63, f = (idx >> 6) & 63, lc = idx >> 12;
            Wt16[idx] = (_Float16)Wr[(size_t)(lc * 64 + d) * 64 + f];
        }
        for (int idx = i0; idx < 3072; idx += nth) {    // Wf16p[c][n16][d]
            int d = idx & 63, n = (idx >> 6) & 15, c = idx >> 10;
            Wf16p[idx] = (n < 8) ? (_Float16)Wfin[(size_t)(c * 64 + d) * 8 + n]
                                 : (_Float16)0.f;
        }
        for (int idx = i0; idx < 1536; idx += nth) {    // Wf32[ck][d]
            int d = idx & 63, ck = idx >> 6;
            Wf32[idx] = Wfin[(size_t)((ck >> 3) * 64 + d) * 8 + (ck & 7)];
        }
        for (int idx = i0; idx < 1536; idx += nth) {    // tab32[cv][f]
            int f = idx & 63, v = (idx >> 6) & 7, c = idx >> 9;
            float xv = v * 0.25f - 1.0f;
            tab32[idx] = fmaxf(W0[c * 64 + f] * xv + b0[c * 64 + f], 0.f);
        }
    }
}

// ---------------- midA: R7-exact layer0 (LUT, hist carry) + dense1 -> Y -----
__global__ __launch_bounds__(256, 4)
void midA(const int* __restrict__ ex,
          const int* __restrict__ Hsub, const int* __restrict__ Hqrt,
          const float* __restrict__ tab32,
          const _Float16* __restrict__ W16, const float* __restrict__ Wd32,
          const float* __restrict__ bias, _Float16* __restrict__ Y,
          float* __restrict__ A64, float* __restrict__ Ggrp)
{
    __shared__ float stab[1536];
    __shared__ __align__(16) _Float16 bounce3[3][64 * 72];
    __shared__ float segwt[3][4][64];
    __shared__ float basearr[192];
    __shared__ float hpart[4][24];
    __shared__ float carry[64];

    int tid = threadIdx.x, bi = blockIdx.x;
    int b = bi >> 10, ci = bi & 1023, g = ci >> 6, cr = ci & 63;
    int w = tid >> 6, ln = tid & 63, lm = ln & 15, lq = ln >> 4;
    int P0 = ci * 64;

    for (int i = tid; i < 1536; i += 256) stab[i] = tab32[i];
    if (ln < 24) {                             // distributed hist prefix
        float s = 0.f;
        for (int j = w; j < g; j += 4) {
            const int* hq = Hqrt + ((size_t)(b * NG + j) * 4) * 24 + ln;
            s += (float)(hq[0] + hq[24] + hq[48] + hq[72]);
        }
        const int* hp = Hsub + (size_t)(b * CI + g * 64) * 24 + ln;
        for (int j = w; j < cr; j += 4) s += (float)hp[j * 24];
        hpart[w][ln] = s;
    }
    __syncthreads();                           // B1: stab + hpart

    // layer-0 local values: thread (f=ln, seg=w) scans 16 px
    float y0[3][16];
    {
#pragma unroll
        for (int p = 0; p < 16; ++p) {
            const int* ep = ex + ((size_t)b * SP + P0 + w * 16 + p) * 3;
            y0[0][p] = stab[ep[0] * 64 + ln];
            y0[1][p] = stab[(8 + ep[1]) * 64 + ln];
            y0[2][p] = stab[(16 + ep[2]) * 64 + ln];
        }
#pragma unroll
        for (int c = 0; c < 3; ++c)
#pragma unroll
            for (int p = 1; p < 16; ++p) y0[c][p] += y0[c][p - 1];
#pragma unroll
        for (int c = 0; c < 3; ++c) segwt[c][w][ln] = y0[c][15];
    }
    if (tid < 64) {                            // layer-0 carry from hist
        float c0 = 0.f;
#pragma unroll
        for (int cv = 0; cv < 24; ++cv) {
            float cnt = hpart[0][cv] + hpart[1][cv] + hpart[2][cv] + hpart[3][cv];
            c0 += cnt * stab[cv * 64 + tid];
        }
        carry[tid] = c0;
    }
    __syncthreads();                           // B2: segwt + carry

    {   // combine channels -> bounce (layer-0 chunk-local flattened cumsum)
        float off0[3];
#pragma unroll
        for (int c = 0; c < 3; ++c) {
            float o = 0.f;
            for (int w2 = 0; w2 < w; ++w2) o += segwt[c][w2][ln];
            off0[c] = o;
        }
#pragma unroll
        for (int p = 0; p < 16; ++p) {
            float S0 = y0[0][p] + off0[0], S1 = y0[1][p] + off0[1], S2 = y0[2][p] + off0[2];
            float P1 = p ? y0[1][p - 1] + off0[1] : off0[1];
            float P2 = p ? y0[2][p - 1] + off0[2] : off0[2];
            int row = w * 16 + p;
            bounce3[0][row * 72 + ln] = (_Float16)(S0 + P1 + P2);
            bounce3[1][row * 72 + ln] = (_Float16)(S0 + S1 + P2);
            bounce3[2][row * 72 + ln] = (_Float16)(S0 + S1 + S2);
        }
    }
    if (tid < 192) {                           // basefold for dense1
        int c = tid >> 6, f = tid & 63;
        const float* wp = Wd32 + (size_t)(c * 64) * 64 + f;
        float a = 0.f;
        for (int d = 0; d < 64; ++d) a += carry[d] * wp[d * 64];
        basearr[tid] = bias[tid] + INVN * a;
    }
    __syncthreads();                           // B3: bounce + basearr

    // dense1 MFMA
    f32x4 acc[3][4];
#pragma unroll
    for (int c = 0; c < 3; ++c) {
        const half8* bb = (const half8*)&bounce3[c][0];
        half8 a0 = bb[(w * 16 + lm) * 9 + lq];
        half8 a1 = bb[(w * 16 + lm) * 9 + 4 + lq];
#pragma unroll
        for (int nt = 0; nt < 4; ++nt) {
            const half8* bp = (const half8*)(W16 + (size_t)(c * 64 + nt * 16 + lm) * 64);
            f32x4 t = {0.f, 0.f, 0.f, 0.f};
            t = __builtin_amdgcn_mfma_f32_16x16x32_f16(a0, bp[lq],     t, 0, 0, 0);
            t = __builtin_amdgcn_mfma_f32_16x16x32_f16(a1, bp[4 + lq], t, 0, 0, 0);
            acc[c][nt] = t;
        }
    }

    // relu + scan + shuffle
    float s[3][4][4], wexcl[3][4];
#pragma unroll
    for (int c = 0; c < 3; ++c)
#pragma unroll
        for (int nt = 0; nt < 4; ++nt) {
            float base = basearr[c * 64 + nt * 16 + lm];
            float run = 0.f;
#pragma unroll
            for (int r = 0; r < 4; ++r) {
                float yv = fmaxf(base + INVN * acc[c][nt][r], 0.f);
                run += yv; s[c][nt][r] = run;
            }
            float v = run;
            float t1 = __shfl_up(v, 16); if (lq >= 1) v += t1;
            float t2 = __shfl_up(v, 32); if (lq >= 2) v += t2;
            wexcl[c][nt] = v - run;
            if (lq == 3) segwt[c][w][nt * 16 + lm] = v;   // wave totals
        }
    __syncthreads();                           // B4: wave tops

    {
        float off[3][4], tot[3][4];
#pragma unroll
        for (int c = 0; c < 3; ++c)
#pragma unroll
            for (int nt = 0; nt < 4; ++nt) {
                float o = wexcl[c][nt], ts = 0.f;
#pragma unroll
                for (int w2 = 0; w2 < 4; ++w2) {
                    float wv = segwt[c][w2][nt * 16 + lm];
                    ts += wv;
                    if (w2 < w) o += wv;
                }
                off[c][nt] = o; tot[c][nt] = ts;
            }
        if (w == 0 && lq == 0)
#pragma unroll
            for (int nt = 0; nt < 4; ++nt) {
                float t3 = tot[0][nt] + tot[1][nt] + tot[2][nt];
                A64[(size_t)(b * CI + ci) * 64 + nt * 16 + lm] = t3;
                atomicAdd(&Ggrp[(size_t)(b * NG + g) * 64 + nt * 16 + lm], t3);
            }
#pragma unroll
        for (int nt = 0; nt < 4; ++nt)
#pragma unroll
            for (int r = 0; r < 4; ++r) {
                float S0 = off[0][nt] + s[0][nt][r];
                float S1 = off[1][nt] + s[1][nt][r];
                float S2 = off[2][nt] + s[2][nt][r];
                float P1 = off[1][nt] + (r ? s[1][nt][r - 1] : 0.f);
                float P2 = off[2][nt] + (r ? s[2][nt][r - 1] : 0.f);
                int row = w * 16 + lq * 4 + r;
                bounce3[0][row * 72 + nt * 16 + lm] = (_Float16)(S0 + P1 + P2);
                bounce3[1][row * 72 + nt * 16 + lm] = (_Float16)(S0 + S1 + P2);
                bounce3[2][row * 72 + nt * 16 + lm] = (_Float16)(S0 + S1 + S2);
            }
    }
    __syncthreads();                           // B5: store staging
#pragma unroll
    for (int q = 0; q < 6; ++q) {
        int idx = q * 256 + tid;
        int c = idx >> 9, rem = idx & 511;
        int pix = rem >> 3, f8 = rem & 7;
        half8 v = *(const half8*)&bounce3[c][pix * 72 + f8 * 8];
        ((half8*)(Y + ((size_t)(b * 3 + c) * SP + P0 + pix) * 64))[f8] = v;
    }
}

// ---------------- midB: dense2, Y in-place (R14-exact) ----------------------
__global__ __launch_bounds__(256, 4)
void midB(const _Float16* Yin, _Float16* Yout,
          const float* __restrict__ A64p, const float* __restrict__ Ggrp_p,
          const _Float16* __restrict__ W16, const float* __restrict__ Wd32,
          const float* __restrict__ bias,
          float* __restrict__ A64, float* __restrict__ Ggrp)
{
    __shared__ __align__(16) _Float16 bounce3[3][64 * 72];
    __shared__ float wtop[3][4][64];
    __shared__ float basearr[192];
    __shared__ float cpart[4][64];
    __shared__ float carry[64];

    int tid = threadIdx.x, bi = blockIdx.x;
    int b = bi >> 10, ci = bi & 1023, g = ci >> 6, cr = ci & 63;
    int w = tid >> 6, ln = tid & 63, lm = ln & 15, lq = ln >> 4;
    int P0 = ci * 64;

    // A-frags first (latency hidden behind prologue)
    half8 af0[3], af1[3];
#pragma unroll
    for (int c = 0; c < 3; ++c) {
        const half8* ap = (const half8*)(Yin + ((size_t)(b * 3 + c) * SP + P0 + w * 16 + lm) * 64);
        af0[c] = ap[lq]; af1[c] = ap[4 + lq];
    }
    {   // distributed carry prefix
        float s = 0.f;
        for (int j = w; j < g; j += 4)
            s += Ggrp_p[(size_t)(b * NG + j) * 64 + ln];
        const float* ap = A64p + (size_t)(b * CI + g * 64) * 64 + ln;
        for (int j = w; j < cr; j += 4) s += ap[j * 64];
        cpart[w][ln] = s;
    }
    __syncthreads();                           // B1
    if (tid < 64)
        carry[tid] = cpart[0][tid] + cpart[1][tid] + cpart[2][tid] + cpart[3][tid];
    __syncthreads();                           // B2
    if (tid < 192) {
        int c = tid >> 6, f = tid & 63;
        const float* wp = Wd32 + (size_t)(c * 64) * 64 + f;
        float a = 0.f;
        for (int d = 0; d < 64; ++d) a += carry[d] * wp[d * 64];
        basearr[tid] = bias[tid] + INVN * a;
    }
    __syncthreads();                           // B3

    f32x4 acc[3][4];
#pragma unroll
    for (int c = 0; c < 3; ++c)
#pragma unroll
        for (int nt = 0; nt < 4; ++nt) {
            const half8* bp = (const half8*)(W16 + (size_t)(c * 64 + nt * 16 + lm) * 64);
            f32x4 t = {0.f, 0.f, 0.f, 0.f};
            t = __builtin_amdgcn_mfma_f32_16x16x32_f16(af0[c], bp[lq],     t, 0, 0, 0);
            t = __builtin_amdgcn_mfma_f32_16x16x32_f16(af1[c], bp[4 + lq], t, 0, 0, 0);
            acc[c][nt] = t;
        }

    float s[3][4][4], wexcl[3][4];
#pragma unroll
    for (int c = 0; c < 3; ++c)
#pragma unroll
        for (int nt = 0; nt < 4; ++nt) {
            float base = basearr[c * 64 + nt * 16 + lm];
            float run = 0.f;
#pragma unroll
            for (int r = 0; r < 4; ++r) {
                float yv = fmaxf(base + INVN * acc[c][nt][r], 0.f);
                run += yv; s[c][nt][r] = run;
            }
            float v = run;
            float t1 = __shfl_up(v, 16); if (lq >= 1) v += t1;
            float t2 = __shfl_up(v, 32); if (lq >= 2) v += t2;
            wexcl[c][nt] = v - run;
            if (lq == 3) wtop[c][w][nt * 16 + lm] = v;
        }
    __syncthreads();                           // B4

    {
        float off[3][4], tot[3][4];
#pragma unroll
        for (int c = 0; c < 3; ++c)
#pragma unroll
            for (int nt = 0; nt < 4; ++nt) {
                float o = wexcl[c][nt], ts = 0.f;
#pragma unroll
                for (int w2 = 0; w2 < 4; ++w2) {
                    float wv = wtop[c][w2][nt * 16 + lm];
                    ts += wv;
                    if (w2 < w) o += wv;
                }
                off[c][nt] = o; tot[c][nt] = ts;
            }
        if (w == 0 && lq == 0)
#pragma unroll
            for (int nt = 0; nt < 4; ++nt) {
                float t3 = tot[0][nt] + tot[1][nt] + tot[2][nt];
                A64[(size_t)(b * CI + ci) * 64 + nt * 16 + lm] = t3;
                atomicAdd(&Ggrp[(size_t)(b * NG + g) * 64 + nt * 16 + lm], t3);
            }
#pragma unroll
        for (int nt = 0; nt < 4; ++nt)
#pragma unroll
            for (int r = 0; r < 4; ++r) {
                float S0 = off[0][nt] + s[0][nt][r];
                float S1 = off[1][nt] + s[1][nt][r];
                float S2 = off[2][nt] + s[2][nt][r];
                float P1 = off[1][nt] + (r ? s[1][nt][r - 1] : 0.f);
                float P2 = off[2][nt] + (r ? s[2][nt][r - 1] : 0.f);
                int row = w * 16 + lq * 4 + r;
                bounce3[0][row * 72 + nt * 16 + lm] = (_Float16)(S0 + P1 + P2);
                bounce3[1][row * 72 + nt * 16 + lm] = (_Float16)(S0 + S1 + P2);
                bounce3[2][row * 72 + nt * 16 + lm] = (_Float16)(S0 + S1 + S2);
            }
    }
    __syncthreads();                           // B5
#pragma unroll
    for (int q = 0; q < 6; ++q) {
        int idx = q * 256 + tid;
        int c = idx >> 9, rem = idx & 511;
        int pix = rem >> 3, f8 = rem & 7;
        half8 v = *(const half8*)&bounce3[c][pix * 72 + f8 * 8];
        ((half8*)(Yout + ((size_t)(b * 3 + c) * SP + P0 + pix) * 64))[f8] = v;
    }
}

// ---------------- midC: dense3 + final MFMA -> out (R14-exact) --------------
__global__ __launch_bounds__(256, 4)
void midC(const _Float16* __restrict__ Yin,
          const float* __restrict__ A64p, const float* __restrict__ Ggrp_p,
          const _Float16* __restrict__ W16, const float* __restrict__ Wd32,
          const float* __restrict__ bias,
          const _Float16* __restrict__ Wf16p, const float* __restrict__ bfin,
          float* __restrict__ out, float* __restrict__ A64, float* __restrict__ Ggrp)
{
    __shared__ __align__(16) _Float16 bounce3[3][64 * 72];
    __shared__ float wtop[3][4][64];
    __shared__ float basearr[192];
    __shared__ float cpart[4][64];
    __shared__ float carry[64];
    __shared__ __align__(16) float outst[64 * 28];

    int tid = threadIdx.x, bi = blockIdx.x;
    int b = bi >> 10, ci = bi & 1023, g = ci >> 6, cr = ci & 63;
    int w = tid >> 6, ln = tid & 63, lm = ln & 15, lq = ln >> 4;
    int P0 = ci * 64;

    half8 af0[3], af1[3];
#pragma unroll
    for (int c = 0; c < 3; ++c) {
        const half8* ap = (const half8*)(Yin + ((size_t)(b * 3 + c) * SP + P0 + w * 16 + lm) * 64);
        af0[c] = ap[lq]; af1[c] = ap[4 + lq];
    }
    {
        float s = 0.f;
        for (int j = w; j < g; j += 4)
            s += Ggrp_p[(size_t)(b * NG + j) * 64 + ln];
        const float* ap = A64p + (size_t)(b * CI + g * 64) * 64 + ln;
        for (int j = w; j < cr; j += 4) s += ap[j * 64];
        cpart[w][ln] = s;
    }
    __syncthreads();                           // B1
    if (tid < 64)
        carry[tid] = cpart[0][tid] + cpart[1][tid] + cpart[2][tid] + cpart[3][tid];
    __syncthreads();                           // B2
    if (tid < 192) {
        int c = tid >> 6, f = tid & 63;
        const float* wp = Wd32 + (size_t)(c * 64) * 64 + f;
        float a = 0.f;
        for (int d = 0; d < 64; ++d) a += carry[d] * wp[d * 64];
        basearr[tid] = bias[tid] + INVN * a;
    }
    __syncthreads();                           // B3

    f32x4 acc[3][4];
#pragma unroll
    for (int c = 0; c < 3; ++c)
#pragma unroll
        for (int nt = 0; nt < 4; ++nt) {
            const half8* bp = (const half8*)(W16 + (size_t)(c * 64 + nt * 16 + lm) * 64);
            f32x4 t = {0.f, 0.f, 0.f, 0.f};
            t = __builtin_amdgcn_mfma_f32_16x16x32_f16(af0[c], bp[lq],     t, 0, 0, 0);
            t = __builtin_amdgcn_mfma_f32_16x16x32_f16(af1[c], bp[4 + lq], t, 0, 0, 0);
            acc[c][nt] = t;
        }

    float s[3][4][4], wexcl[3][4];
#pragma unroll
    for (int c = 0; c < 3; ++c)
#pragma unroll
        for (int nt = 0; nt < 4; ++nt) {
            float base = basearr[c * 64 + nt * 16 + lm];
            float run = 0.f;
#pragma unroll
            for (int r = 0; r < 4; ++r) {
                float yv = fmaxf(base + INVN * acc[c][nt][r], 0.f);
                run += yv; s[c][nt][r] = run;
            }
            float v = run;
            float t1 = __shfl_up(v, 16); if (lq >= 1) v += t1;
            float t2 = __shfl_up(v, 32); if (lq >= 2) v += t2;
            wexcl[c][nt] = v - run;
            if (lq == 3) wtop[c][w][nt * 16 + lm] = v;
        }
    __syncthreads();                           // B4

    {
        float off[3][4], tot[3][4];
#pragma unroll
        for (int c = 0; c < 3; ++c)
#pragma unroll
            for (int nt = 0; nt < 4; ++nt) {
                float o = wexcl[c][nt], ts = 0.f;
#pragma unroll
                for (int w2 = 0; w2 < 4; ++w2) {
                    float wv = wtop[c][w2][nt * 16 + lm];
                    ts += wv;
                    if (w2 < w) o += wv;
                }
                off[c][nt] = o; tot[c][nt] = ts;
            }
        if (w == 0 && lq == 0)
#pragma unroll
            for (int nt = 0; nt < 4; ++nt) {
                float t3 = tot[0][nt] + tot[1][nt] + tot[2][nt];
                A64[(size_t)(b * CI + ci) * 64 + nt * 16 + lm] = t3;
                atomicAdd(&Ggrp[(size_t)(b * NG + g) * 64 + nt * 16 + lm], t3);
            }
#pragma unroll
        for (int nt = 0; nt < 4; ++nt)
#pragma unroll
            for (int r = 0; r < 4; ++r) {
                float S0 = off[0][nt] + s[0][nt][r];
                float S1 = off[1][nt] + s[1][nt][r];
                float S2 = off[2][nt] + s[2][nt][r];
                float P1 = off[1][nt] + (r ? s[1][nt][r - 1] : 0.f);
                float P2 = off[2][nt] + (r ? s[2][nt][r - 1] : 0.f);
                int row = w * 16 + lq * 4 + r;
                bounce3[0][row * 72 + nt * 16 + lm] = (_Float16)(S0 + P1 + P2);
                bounce3[1][row * 72 + nt * 16 + lm] = (_Float16)(S0 + S1 + P2);
                bounce3[2][row * 72 + nt * 16 + lm] = (_Float16)(S0 + S1 + S2);
            }
    }
    __syncthreads();                           // B5: layer-3 local staged

    // final dense via padded-Wf MFMA (n=16: 8 logits + 8 zero)
#pragma unroll
    for (int c = 0; c < 3; ++c) {
        const half8* bb = (const half8*)&bounce3[c][0];
        half8 fa0 = bb[(w * 16 + lm) * 9 + lq];
        half8 fa1 = bb[(w * 16 + lm) * 9 + 4 + lq];
        const half8* fb = (const half8*)(Wf16p + (size_t)(c * 16 + lm) * 64);
        f32x4 t = {0.f, 0.f, 0.f, 0.f};
        t = __builtin_amdgcn_mfma_f32_16x16x32_f16(fa0, fb[lq],     t, 0, 0, 0);
        t = __builtin_amdgcn_mfma_f32_16x16x32_f16(fa1, fb[4 + lq], t, 0, 0, 0);
        if (lm < 8) {
            float bz = bfin[c * 8 + lm];
#pragma unroll
            for (int r = 0; r < 4; ++r)
                outst[(w * 16 + lq * 4 + r) * 28 + c * 8 + lm] = bz + INVN * t[r];
        }
    }
    __syncthreads();                           // B6
    {   // 64 px x 24 floats = 384 float4
        float4* obase = (float4*)(out + ((size_t)b * SS + (size_t)P0 * 3) * 8);
#pragma unroll
        for (int k = 0; k < 2; ++k) {
            int idx = k * 256 + tid;
            if (idx < 384) {
                int pix = idx / 6, sub = (idx % 6) * 4;
                obase[idx] = *(const float4*)&outst[pix * 28 + sub];
            }
        }
    }
}

// ---------------- fixk: out += INVN * Wf . carry3, 4 chunks per block -------
__global__ __launch_bounds__(256, 4)
void fixk(const float* __restrict__ A64p, const float* __restrict__ Ggrp_p,
          const float* __restrict__ Wf32, float* __restrict__ out)
{
    __shared__ float cpart[4][64];
    __shared__ float carry4[4][64];
    __shared__ float part[4][24][8];
    __shared__ float vfix[4][24];
    int tid = threadIdx.x, bi = blockIdx.x;     // 1024 blocks: b*256 + quad
    int b = bi >> 8, quad = bi & 255;
    int ci0 = quad * 4, g = ci0 >> 6, cr0 = ci0 & 63;
    int w = tid >> 6, ln = tid & 63;

    {   // distributed carry prefix to ci0
        float s = 0.f;
        for (int j = w; j < g; j += 4)
            s += Ggrp_p[(size_t)(b * NG + j) * 64 + ln];
        const float* ap = A64p + (size_t)(b * CI + g * 64) * 64 + ln;
        for (int j = w; j < cr0; j += 4) s += ap[j * 64];
        cpart[w][ln] = s;
    }
    __syncthreads();
    if (tid < 64) {                             // extend to 4 per-chunk carries
        float c = cpart[0][tid] + cpart[1][tid] + cpart[2][tid] + cpart[3][tid];
        const float* arow = A64p + (size_t)(b * CI + ci0) * 64 + tid;
        carry4[0][tid] = c;
        c += arow[0];   carry4[1][tid] = c;
        c += arow[64];  carry4[2][tid] = c;
        c += arow[128]; carry4[3][tid] = c;
    }
    __syncthreads();
    if (tid < 192) {                            // 4 chunks x 24 outputs x 8 segs
        int ck = tid >> 3, sg = tid & 7;
        const float* wp = Wf32 + ck * 64 + sg * 8;
#pragma unroll
        for (int k = 0; k < 4; ++k) {
            const float* cp = &carry4[k][sg * 8];
            float vf = 0.f;
#pragma unroll
            for (int d = 0; d < 8; ++d) vf += cp[d] * wp[d];
            part[k][ck][sg] = vf;
        }
    }
    __syncthreads();
    if (tid < 96) {
        int k = tid / 24, ck = tid % 24;
        float vf = 0.f;
#pragma unroll
        for (int j = 0; j < 8; ++j) vf += part[k][ck][j];
        vfix[k][ck] = INVN * vf;
    }
    __syncthreads();
    // RMW: 4 chunks x 384 float4 = 1536, contiguous (chunks consecutive)
    float4* obase = (float4*)(out + ((size_t)b * SS + (size_t)(ci0 * 64) * 3) * 8);
#pragma unroll
    for (int kk = 0; kk < 6; ++kk) {
        int idx = kk * 256 + tid;               // 0..1535
        int k = idx / 384, rem = idx - k * 384;
        int sub = (rem % 6) * 4;
        float4 v = obase[idx];
        v.x += vfix[k][sub];
        v.y += vfix[k][sub + 1];
        v.z += vfix[k][sub + 2];
        v.w += vfix[k][sub + 3];
        obase[idx] = v;
    }
}

// ---------------- host -------------------------------------------------------
extern "C" void kernel_launch(void* const* d_in, const int* in_sizes, int n_in,
                              void* d_out, int out_size, void* d_ws, size_t ws_size,
                              hipStream_t stream)
{
    const int*   ex   = (const int*)d_in[0];
    const float* W0   = (const float*)d_in[1];
    const float* b0   = (const float*)d_in[2];
    const float* Wr   = (const float*)d_in[3];
    const float* br   = (const float*)d_in[4];
    const float* Wfin = (const float*)d_in[5];
    const float* bfin = (const float*)d_in[6];
    float* out = (float*)d_out;

    char* ws = (char*)d_ws;
    size_t off = 0;
    _Float16* Y = (_Float16*)(ws + off); off += (size_t)BB * 3 * SP * 64 * 2;  // 100.7 MB
    float* Ggrp1 = (float*)(ws + off); off += (size_t)BB * NG * 64 * 4;        // contiguous
    float* Ggrp2 = (float*)(ws + off); off += (size_t)BB * NG * 64 * 4;
    float* Ggrp3 = (float*)(ws + off); off += (size_t)BB * NG * 64 * 4;
    float* A64_1 = (float*)(ws + off); off += (size_t)BB * CI * 64 * 4;
    float* A64_2 = (float*)(ws + off); off += (size_t)BB * CI * 64 * 4;
    float* A64_3 = (float*)(ws + off); off += (size_t)BB * CI * 64 * 4;
    int* Hsub = (int*)(ws + off); off += (size_t)BB * CI * 24 * 4;
    int* Hqrt = (int*)(ws + off); off += (size_t)BB * NG * 4 * 24 * 4;
    _Float16* Wt16  = (_Float16*)(ws + off); off += 36864 * 2;
    _Float16* Wf16p = (_Float16*)(ws + off); off += 3072 * 2;
    float* Wf32  = (float*)(ws + off); off += 1536 * 4;
    float* tab32 = (float*)(ws + off); off += 1536 * 4;

    prep<<<256, 256, 0, stream>>>(ex, W0, b0, Wr, Wfin,
                                  Wt16, Wf16p, Wf32, tab32,
                                  Hsub, Hqrt, Ggrp1);
    midA<<<4096, 256, 0, stream>>>(ex, Hsub, Hqrt, tab32,
                                   Wt16, Wr, br, Y, A64_1, Ggrp1);
    midB<<<4096, 256, 0, stream>>>(Y, Y, A64_1, Ggrp1,
                                   Wt16 + 12288, Wr + 12288, br + 192,
                                   A64_2, Ggrp2);
    midC<<<4096, 256, 0, stream>>>(Y, A64_2, Ggrp2,
                                   Wt16 + 24576, Wr + 24576, br + 384,
                                   Wf16p, bfin, out, A64_3, Ggrp3);
    fixk<<<1024, 256, 0, stream>>>(A64_3, Ggrp3, Wf32, out);
}

// Round 14
// 353.957 us; speedup vs baseline: 1.2155x; 1.0030x over previous
//
#include <hip/hip_runtime.h>
#include <stdint.h>

// ---------------------------------------------------------------------------
// R21: R20 champion (355.0 us) + ONE isolated change: XCD-aware blockIdx
// swizzle (T1) on midA/midB/midC/fixk. Mechanism: a group's 64 chunk-blocks
// share Ggrp rows + overlapping A64/Hsub prefix reads + Ggrp atomics; default
// dispatch round-robins consecutive blocks across 8 non-coherent per-XCD L2s,
// so shared rows are re-fetched 8x and atomics bounce cross-XCD. Remap
// bi = (raw&7)*512 + raw>>3 (bijective, 4096%8==0) -> each XCD owns 512
// consecutive chunks = 8 whole groups; prologue loads L2-local.
// R15 proved prologue latency is ~10 us/mid of the convoy span -> expect
// mids 98.3 -> 90-95. Zero-risk remap; everything else R20-byte-identical.
// ---------------------------------------------------------------------------

#define BB 4
#define SP 65536
#define SS 196608
#define CI 1024                 // 64-px chunks per batch
#define NG 16                   // groups per batch (64 chunks each)
#define INVN (1.0f / 196608.0f)

typedef __attribute__((ext_vector_type(8))) _Float16 half8;
typedef __attribute__((ext_vector_type(4))) float    f32x4;

// ---------------- prep: histograms + weight prep + Ggrp zero ----------------
__global__ __launch_bounds__(256)
void prep(const int* __restrict__ ex, const float* __restrict__ W0,
          const float* __restrict__ b0, const float* __restrict__ Wr,
          const float* __restrict__ Wfin,
          _Float16* __restrict__ Wt16, _Float16* __restrict__ Wf16p,
          float* __restrict__ Wf32, float* __restrict__ tab32,
          int* __restrict__ Hsub, int* __restrict__ Hqrt,
          float* __restrict__ Gz)
{
    __shared__ int hist[16][24];
    int tid = threadIdx.x, bi = blockIdx.x;        // 256 blocks
    int b = bi >> 6, g = (bi >> 2) & 15, q = bi & 3;  // quarter-group = 16 chunks
    for (int i = tid; i < 384; i += 256) hist[i / 24][i % 24] = 0;
    __syncthreads();
    for (int it = 0; it < 4; ++it) {
        int pl = it * 256 + tid;                   // 0..1023 within quarter
        const int* ep = ex + ((size_t)b * SP + g * 4096 + q * 1024 + pl) * 3;
        int j = pl >> 6;                           // chunk within quarter
        atomicAdd(&hist[j][ep[0]], 1);
        atomicAdd(&hist[j][8 + ep[1]], 1);
        atomicAdd(&hist[j][16 + ep[2]], 1);
    }
    __syncthreads();
    for (int i = tid; i < 384; i += 256) {
        int j = i / 24, cv = i % 24;
        Hsub[(size_t)(b * CI + g * 64 + q * 16 + j) * 24 + cv] = hist[j][cv];
    }
    if (tid < 24) {
        int s = 0;
        for (int j = 0; j < 16; ++j) s += hist[j][tid];
        Hqrt[((size_t)(b * NG + g) * 4 + q) * 24 + tid] = s;   // non-atomic
    }
    {   // weight prep + Ggrp zeroing (all 256 blocks share)
        int i0 = bi * 256 + tid, nth = 256 * 256;
        for (int idx = i0; idx < 12288; idx += nth)     // Ggrp1..3 zero
            Gz[idx] = 0.f;
        for (int idx = i0; idx < 36864; idx += nth) {   // Wt16[l][c][f][d]
            int d = idx & 63, f = (idx >> 6) & 63, lc = idx >> 12;
            Wt16[idx] = (_Float16)Wr[(size_t)(lc * 64 + d) * 64 + f];
        }
        for (int idx = i0; idx < 3072; idx += nth) {    // Wf16p[c][n16][d]
            int d = idx & 63, n = (idx >> 6) & 15, c = idx >> 10;
            Wf16p[idx] = (n < 8) ? (_Float16)Wfin[(size_t)(c * 64 + d) * 8 + n]
                                 : (_Float16)0.f;
        }
        for (int idx = i0; idx < 1536; idx += nth) {    // Wf32[ck][d]
            int d = idx & 63, ck = idx >> 6;
            Wf32[idx] = Wfin[(size_t)((ck >> 3) * 64 + d) * 8 + (ck & 7)];
        }
        for (int idx = i0; idx < 1536; idx += nth) {    // tab32[cv][f]
            int f = idx & 63, v = (idx >> 6) & 7, c = idx >> 9;
            float xv = v * 0.25f - 1.0f;
            tab32[idx] = fmaxf(W0[c * 64 + f] * xv + b0[c * 64 + f], 0.f);
        }
    }
}

// ---------------- midA: R14-exact body + XCD swizzle ------------------------
__global__ __launch_bounds__(256, 4)
void midA(const int* __restrict__ ex,
          const int* __restrict__ Hsub, const int* __restrict__ Hqrt,
          const float* __restrict__ tab32,
          const _Float16* __restrict__ W16, const float* __restrict__ Wd32,
          const float* __restrict__ bias, _Float16* __restrict__ Y,
          float* __restrict__ A64, float* __restrict__ Ggrp)
{
    __shared__ float stab[1536];
    __shared__ __align__(16) _Float16 bounce3[3][64 * 72];
    __shared__ float segwt[3][4][64];
    __shared__ float basearr[192];
    __shared__ float hpart[4][24];
    __shared__ float carry[64];

    int tid = threadIdx.x;
    int raw = blockIdx.x;
    int bi = ((raw & 7) << 9) | (raw >> 3);    // XCD swizzle: 4096 blocks
    int b = bi >> 10, ci = bi & 1023, g = ci >> 6, cr = ci & 63;
    int w = tid >> 6, ln = tid & 63, lm = ln & 15, lq = ln >> 4;
    int P0 = ci * 64;

    for (int i = tid; i < 1536; i += 256) stab[i] = tab32[i];
    if (ln < 24) {                             // distributed hist prefix
        float s = 0.f;
        for (int j = w; j < g; j += 4) {
            const int* hq = Hqrt + ((size_t)(b * NG + j) * 4) * 24 + ln;
            s += (float)(hq[0] + hq[24] + hq[48] + hq[72]);
        }
        const int* hp = Hsub + (size_t)(b * CI + g * 64) * 24 + ln;
        for (int j = w; j < cr; j += 4) s += (float)hp[j * 24];
        hpart[w][ln] = s;
    }
    __syncthreads();                           // B1: stab + hpart

    // layer-0 local values: thread (f=ln, seg=w) scans 16 px
    float y0[3][16];
    {
#pragma unroll
        for (int p = 0; p < 16; ++p) {
            const int* ep = ex + ((size_t)b * SP + P0 + w * 16 + p) * 3;
            y0[0][p] = stab[ep[0] * 64 + ln];
            y0[1][p] = stab[(8 + ep[1]) * 64 + ln];
            y0[2][p] = stab[(16 + ep[2]) * 64 + ln];
        }
#pragma unroll
        for (int c = 0; c < 3; ++c)
#pragma unroll
            for (int p = 1; p < 16; ++p) y0[c][p] += y0[c][p - 1];
#pragma unroll
        for (int c = 0; c < 3; ++c) segwt[c][w][ln] = y0[c][15];
    }
    if (tid < 64) {                            // layer-0 carry from hist
        float c0 = 0.f;
#pragma unroll
        for (int cv = 0; cv < 24; ++cv) {
            float cnt = hpart[0][cv] + hpart[1][cv] + hpart[2][cv] + hpart[3][cv];
            c0 += cnt * stab[cv * 64 + tid];
        }
        carry[tid] = c0;
    }
    __syncthreads();                           // B2: segwt + carry

    {   // combine channels -> bounce (layer-0 chunk-local flattened cumsum)
        float off0[3];
#pragma unroll
        for (int c = 0; c < 3; ++c) {
            float o = 0.f;
            for (int w2 = 0; w2 < w; ++w2) o += segwt[c][w2][ln];
            off0[c] = o;
        }
#pragma unroll
        for (int p = 0; p < 16; ++p) {
            float S0 = y0[0][p] + off0[0], S1 = y0[1][p] + off0[1], S2 = y0[2][p] + off0[2];
            float P1 = p ? y0[1][p - 1] + off0[1] : off0[1];
            float P2 = p ? y0[2][p - 1] + off0[2] : off0[2];
            int row = w * 16 + p;
            bounce3[0][row * 72 + ln] = (_Float16)(S0 + P1 + P2);
            bounce3[1][row * 72 + ln] = (_Float16)(S0 + S1 + P2);
            bounce3[2][row * 72 + ln] = (_Float16)(S0 + S1 + S2);
        }
    }
    if (tid < 192) {                           // basefold for dense1
        int c = tid >> 6, f = tid & 63;
        const float* wp = Wd32 + (size_t)(c * 64) * 64 + f;
        float a = 0.f;
        for (int d = 0; d < 64; ++d) a += carry[d] * wp[d * 64];
        basearr[tid] = bias[tid] + INVN * a;
    }
    __syncthreads();                           // B3: bounce + basearr

    // dense1 MFMA
    f32x4 acc[3][4];
#pragma unroll
    for (int c = 0; c < 3; ++c) {
        const half8* bb = (const half8*)&bounce3[c][0];
        half8 a0 = bb[(w * 16 + lm) * 9 + lq];
        half8 a1 = bb[(w * 16 + lm) * 9 + 4 + lq];
#pragma unroll
        for (int nt = 0; nt < 4; ++nt) {
            const half8* bp = (const half8*)(W16 + (size_t)(c * 64 + nt * 16 + lm) * 64);
            f32x4 t = {0.f, 0.f, 0.f, 0.f};
            t = __builtin_amdgcn_mfma_f32_16x16x32_f16(a0, bp[lq],     t, 0, 0, 0);
            t = __builtin_amdgcn_mfma_f32_16x16x32_f16(a1, bp[4 + lq], t, 0, 0, 0);
            acc[c][nt] = t;
        }
    }

    // relu + scan + shuffle
    float s[3][4][4], wexcl[3][4];
#pragma unroll
    for (int c = 0; c < 3; ++c)
#pragma unroll
        for (int nt = 0; nt < 4; ++nt) {
            float base = basearr[c * 64 + nt * 16 + lm];
            float run = 0.f;
#pragma unroll
            for (int r = 0; r < 4; ++r) {
                float yv = fmaxf(base + INVN * acc[c][nt][r], 0.f);
                run += yv; s[c][nt][r] = run;
            }
            float v = run;
            float t1 = __shfl_up(v, 16); if (lq >= 1) v += t1;
            float t2 = __shfl_up(v, 32); if (lq >= 2) v += t2;
            wexcl[c][nt] = v - run;
            if (lq == 3) segwt[c][w][nt * 16 + lm] = v;   // wave totals
        }
    __syncthreads();                           // B4: wave tops

    {
        float off[3][4], tot[3][4];
#pragma unroll
        for (int c = 0; c < 3; ++c)
#pragma unroll
            for (int nt = 0; nt < 4; ++nt) {
                float o = wexcl[c][nt], ts = 0.f;
#pragma unroll
                for (int w2 = 0; w2 < 4; ++w2) {
                    float wv = segwt[c][w2][nt * 16 + lm];
                    ts += wv;
                    if (w2 < w) o += wv;
                }
                off[c][nt] = o; tot[c][nt] = ts;
            }
        if (w == 0 && lq == 0)
#pragma unroll
            for (int nt = 0; nt < 4; ++nt) {
                float t3 = tot[0][nt] + tot[1][nt] + tot[2][nt];
                A64[(size_t)(b * CI + ci) * 64 + nt * 16 + lm] = t3;
                atomicAdd(&Ggrp[(size_t)(b * NG + g) * 64 + nt * 16 + lm], t3);
            }
#pragma unroll
        for (int nt = 0; nt < 4; ++nt)
#pragma unroll
            for (int r = 0; r < 4; ++r) {
                float S0 = off[0][nt] + s[0][nt][r];
                float S1 = off[1][nt] + s[1][nt][r];
                float S2 = off[2][nt] + s[2][nt][r];
                float P1 = off[1][nt] + (r ? s[1][nt][r - 1] : 0.f);
                float P2 = off[2][nt] + (r ? s[2][nt][r - 1] : 0.f);
                int row = w * 16 + lq * 4 + r;
                bounce3[0][row * 72 + nt * 16 + lm] = (_Float16)(S0 + P1 + P2);
                bounce3[1][row * 72 + nt * 16 + lm] = (_Float16)(S0 + S1 + P2);
                bounce3[2][row * 72 + nt * 16 + lm] = (_Float16)(S0 + S1 + S2);
            }
    }
    __syncthreads();                           // B5: store staging
#pragma unroll
    for (int q = 0; q < 6; ++q) {
        int idx = q * 256 + tid;
        int c = idx >> 9, rem = idx & 511;
        int pix = rem >> 3, f8 = rem & 7;
        half8 v = *(const half8*)&bounce3[c][pix * 72 + f8 * 8];
        ((half8*)(Y + ((size_t)(b * 3 + c) * SP + P0 + pix) * 64))[f8] = v;
    }
}

// ---------------- midB: R14-exact body + XCD swizzle ------------------------
__global__ __launch_bounds__(256, 4)
void midB(const _Float16* Yin, _Float16* Yout,
          const float* __restrict__ A64p, const float* __restrict__ Ggrp_p,
          const _Float16* __restrict__ W16, const float* __restrict__ Wd32,
          const float* __restrict__ bias,
          float* __restrict__ A64, float* __restrict__ Ggrp)
{
    __shared__ __align__(16) _Float16 bounce3[3][64 * 72];
    __shared__ float wtop[3][4][64];
    __shared__ float basearr[192];
    __shared__ float cpart[4][64];
    __shared__ float carry[64];

    int tid = threadIdx.x;
    int raw = blockIdx.x;
    int bi = ((raw & 7) << 9) | (raw >> 3);    // XCD swizzle: 4096 blocks
    int b = bi >> 10, ci = bi & 1023, g = ci >> 6, cr = ci & 63;
    int w = tid >> 6, ln = tid & 63, lm = ln & 15, lq = ln >> 4;
    int P0 = ci * 64;

    // A-frags first (latency hidden behind prologue)
    half8 af0[3], af1[3];
#pragma unroll
    for (int c = 0; c < 3; ++c) {
        const half8* ap = (const half8*)(Yin + ((size_t)(b * 3 + c) * SP + P0 + w * 16 + lm) * 64);
        af0[c] = ap[lq]; af1[c] = ap[4 + lq];
    }
    {   // distributed carry prefix
        float s = 0.f;
        for (int j = w; j < g; j += 4)
            s += Ggrp_p[(size_t)(b * NG + j) * 64 + ln];
        const float* ap = A64p + (size_t)(b * CI + g * 64) * 64 + ln;
        for (int j = w; j < cr; j += 4) s += ap[j * 64];
        cpart[w][ln] = s;
    }
    __syncthreads();                           // B1
    if (tid < 64)
        carry[tid] = cpart[0][tid] + cpart[1][tid] + cpart[2][tid] + cpart[3][tid];
    __syncthreads();                           // B2
    if (tid < 192) {
        int c = tid >> 6, f = tid & 63;
        const float* wp = Wd32 + (size_t)(c * 64) * 64 + f;
        float a = 0.f;
        for (int d = 0; d < 64; ++d) a += carry[d] * wp[d * 64];
        basearr[tid] = bias[tid] + INVN * a;
    }
    __syncthreads();                           // B3

    f32x4 acc[3][4];
#pragma unroll
    for (int c = 0; c < 3; ++c)
#pragma unroll
        for (int nt = 0; nt < 4; ++nt) {
            const half8* bp = (const half8*)(W16 + (size_t)(c * 64 + nt * 16 + lm) * 64);
            f32x4 t = {0.f, 0.f, 0.f, 0.f};
            t = __builtin_amdgcn_mfma_f32_16x16x32_f16(af0[c], bp[lq],     t, 0, 0, 0);
            t = __builtin_amdgcn_mfma_f32_16x16x32_f16(af1[c], bp[4 + lq], t, 0, 0, 0);
            acc[c][nt] = t;
        }

    float s[3][4][4], wexcl[3][4];
#pragma unroll
    for (int c = 0; c < 3; ++c)
#pragma unroll
        for (int nt = 0; nt < 4; ++nt) {
            float base = basearr[c * 64 + nt * 16 + lm];
            float run = 0.f;
#pragma unroll
            for (int r = 0; r < 4; ++r) {
                float yv = fmaxf(base + INVN * acc[c][nt][r], 0.f);
                run += yv; s[c][nt][r] = run;
            }
            float v = run;
            float t1 = __shfl_up(v, 16); if (lq >= 1) v += t1;
            float t2 = __shfl_up(v, 32); if (lq >= 2) v += t2;
            wexcl[c][nt] = v - run;
            if (lq == 3) wtop[c][w][nt * 16 + lm] = v;
        }
    __syncthreads();                           // B4

    {
        float off[3][4], tot[3][4];
#pragma unroll
        for (int c = 0; c < 3; ++c)
#pragma unroll
            for (int nt = 0; nt < 4; ++nt) {
                float o = wexcl[c][nt], ts = 0.f;
#pragma unroll
                for (int w2 = 0; w2 < 4; ++w2) {
                    float wv = wtop[c][w2][nt * 16 + lm];
                    ts += wv;
                    if (w2 < w) o += wv;
                }
                off[c][nt] = o; tot[c][nt] = ts;
            }
        if (w == 0 && lq == 0)
#pragma unroll
            for (int nt = 0; nt < 4; ++nt) {
                float t3 = tot[0][nt] + tot[1][nt] + tot[2][nt];
                A64[(size_t)(b * CI + ci) * 64 + nt * 16 + lm] = t3;
                atomicAdd(&Ggrp[(size_t)(b * NG + g) * 64 + nt * 16 + lm], t3);
            }
#pragma unroll
        for (int nt = 0; nt < 4; ++nt)
#pragma unroll
            for (int r = 0; r < 4; ++r) {
                float S0 = off[0][nt] + s[0][nt][r];
                float S1 = off[1][nt] + s[1][nt][r];
                float S2 = off[2][nt] + s[2][nt][r];
                float P1 = off[1][nt] + (r ? s[1][nt][r - 1] : 0.f);
                float P2 = off[2][nt] + (r ? s[2][nt][r - 1] : 0.f);
                int row = w * 16 + lq * 4 + r;
                bounce3[0][row * 72 + nt * 16 + lm] = (_Float16)(S0 + P1 + P2);
                bounce3[1][row * 72 + nt * 16 + lm] = (_Float16)(S0 + S1 + P2);
                bounce3[2][row * 72 + nt * 16 + lm] = (_Float16)(S0 + S1 + S2);
            }
    }
    __syncthreads();                           // B5
#pragma unroll
    for (int q = 0; q < 6; ++q) {
        int idx = q * 256 + tid;
        int c = idx >> 9, rem = idx & 511;
        int pix = rem >> 3, f8 = rem & 7;
        half8 v = *(const half8*)&bounce3[c][pix * 72 + f8 * 8];
        ((half8*)(Yout + ((size_t)(b * 3 + c) * SP + P0 + pix) * 64))[f8] = v;
    }
}

// ---------------- midC: R14-exact body + XCD swizzle ------------------------
__global__ __launch_bounds__(256, 4)
void midC(const _Float16* __restrict__ Yin,
          const float* __restrict__ A64p, const float* __restrict__ Ggrp_p,
          const _Float16* __restrict__ W16, const float* __restrict__ Wd32,
          const float* __restrict__ bias,
          const _Float16* __restrict__ Wf16p, const float* __restrict__ bfin,
          float* __restrict__ out, float* __restrict__ A64, float* __restrict__ Ggrp)
{
    __shared__ __align__(16) _Float16 bounce3[3][64 * 72];
    __shared__ float wtop[3][4][64];
    __shared__ float basearr[192];
    __shared__ float cpart[4][64];
    __shared__ float carry[64];
    __shared__ __align__(16) float outst[64 * 28];

    int tid = threadIdx.x;
    int raw = blockIdx.x;
    int bi = ((raw & 7) << 9) | (raw >> 3);    // XCD swizzle: 4096 blocks
    int b = bi >> 10, ci = bi & 1023, g = ci >> 6, cr = ci & 63;
    int w = tid >> 6, ln = tid & 63, lm = ln & 15, lq = ln >> 4;
    int P0 = ci * 64;

    half8 af0[3], af1[3];
#pragma unroll
    for (int c = 0; c < 3; ++c) {
        const half8* ap = (const half8*)(Yin + ((size_t)(b * 3 + c) * SP + P0 + w * 16 + lm) * 64);
        af0[c] = ap[lq]; af1[c] = ap[4 + lq];
    }
    {
        float s = 0.f;
        for (int j = w; j < g; j += 4)
            s += Ggrp_p[(size_t)(b * NG + j) * 64 + ln];
        const float* ap = A64p + (size_t)(b * CI + g * 64) * 64 + ln;
        for (int j = w; j < cr; j += 4) s += ap[j * 64];
        cpart[w][ln] = s;
    }
    __syncthreads();                           // B1
    if (tid < 64)
        carry[tid] = cpart[0][tid] + cpart[1][tid] + cpart[2][tid] + cpart[3][tid];
    __syncthreads();                           // B2
    if (tid < 192) {
        int c = tid >> 6, f = tid & 63;
        const float* wp = Wd32 + (size_t)(c * 64) * 64 + f;
        float a = 0.f;
        for (int d = 0; d < 64; ++d) a += carry[d] * wp[d * 64];
        basearr[tid] = bias[tid] + INVN * a;
    }
    __syncthreads();                           // B3

    f32x4 acc[3][4];
#pragma unroll
    for (int c = 0; c < 3; ++c)
#pragma unroll
        for (int nt = 0; nt < 4; ++nt) {
            const half8* bp = (const half8*)(W16 + (size_t)(c * 64 + nt * 16 + lm) * 64);
            f32x4 t = {0.f, 0.f, 0.f, 0.f};
            t = __builtin_amdgcn_mfma_f32_16x16x32_f16(af0[c], bp[lq],     t, 0, 0, 0);
            t = __builtin_amdgcn_mfma_f32_16x16x32_f16(af1[c], bp[4 + lq], t, 0, 0, 0);
            acc[c][nt] = t;
        }

    float s[3][4][4], wexcl[3][4];
#pragma unroll
    for (int c = 0; c < 3; ++c)
#pragma unroll
        for (int nt = 0; nt < 4; ++nt) {
            float base = basearr[c * 64 + nt * 16 + lm];
            float run = 0.f;
#pragma unroll
            for (int r = 0; r < 4; ++r) {
                float yv = fmaxf(base + INVN * acc[c][nt][r], 0.f);
                run += yv; s[c][nt][r] = run;
            }
            float v = run;
            float t1 = __shfl_up(v, 16); if (lq >= 1) v += t1;
            float t2 = __shfl_up(v, 32); if (lq >= 2) v += t2;
            wexcl[c][nt] = v - run;
            if (lq == 3) wtop[c][w][nt * 16 + lm] = v;
        }
    __syncthreads();                           // B4

    {
        float off[3][4], tot[3][4];
#pragma unroll
        for (int c = 0; c < 3; ++c)
#pragma unroll
            for (int nt = 0; nt < 4; ++nt) {
                float o = wexcl[c][nt], ts = 0.f;
#pragma unroll
                for (int w2 = 0; w2 < 4; ++w2) {
                    float wv = wtop[c][w2][nt * 16 + lm];
                    ts += wv;
                    if (w2 < w) o += wv;
                }
                off[c][nt] = o; tot[c][nt] = ts;
            }
        if (w == 0 && lq == 0)
#pragma unroll
            for (int nt = 0; nt < 4; ++nt) {
                float t3 = tot[0][nt] + tot[1][nt] + tot[2][nt];
                A64[(size_t)(b * CI + ci) * 64 + nt * 16 + lm] = t3;
                atomicAdd(&Ggrp[(size_t)(b * NG + g) * 64 + nt * 16 + lm], t3);
            }
#pragma unroll
        for (int nt = 0; nt < 4; ++nt)
#pragma unroll
            for (int r = 0; r < 4; ++r) {
                float S0 = off[0][nt] + s[0][nt][r];
                float S1 = off[1][nt] + s[1][nt][r];
                float S2 = off[2][nt] + s[2][nt][r];
                float P1 = off[1][nt] + (r ? s[1][nt][r - 1] : 0.f);
                float P2 = off[2][nt] + (r ? s[2][nt][r - 1] : 0.f);
                int row = w * 16 + lq * 4 + r;
                bounce3[0][row * 72 + nt * 16 + lm] = (_Float16)(S0 + P1 + P2);
                bounce3[1][row * 72 + nt * 16 + lm] = (_Float16)(S0 + S1 + P2);
                bounce3[2][row * 72 + nt * 16 + lm] = (_Float16)(S0 + S1 + S2);
            }
    }
    __syncthreads();                           // B5: layer-3 local staged

    // final dense via padded-Wf MFMA (n=16: 8 logits + 8 zero)
#pragma unroll
    for (int c = 0; c < 3; ++c) {
        const half8* bb = (const half8*)&bounce3[c][0];
        half8 fa0 = bb[(w * 16 + lm) * 9 + lq];
        half8 fa1 = bb[(w * 16 + lm) * 9 + 4 + lq];
        const half8* fb = (const half8*)(Wf16p + (size_t)(c * 16 + lm) * 64);
        f32x4 t = {0.f, 0.f, 0.f, 0.f};
        t = __builtin_amdgcn_mfma_f32_16x16x32_f16(fa0, fb[lq],     t, 0, 0, 0);
        t = __builtin_amdgcn_mfma_f32_16x16x32_f16(fa1, fb[4 + lq], t, 0, 0, 0);
        if (lm < 8) {
            float bz = bfin[c * 8 + lm];
#pragma unroll
            for (int r = 0; r < 4; ++r)
                outst[(w * 16 + lq * 4 + r) * 28 + c * 8 + lm] = bz + INVN * t[r];
        }
    }
    __syncthreads();                           // B6
    {   // 64 px x 24 floats = 384 float4
        float4* obase = (float4*)(out + ((size_t)b * SS + (size_t)P0 * 3) * 8);
#pragma unroll
        for (int k = 0; k < 2; ++k) {
            int idx = k * 256 + tid;
            if (idx < 384) {
                int pix = idx / 6, sub = (idx % 6) * 4;
                obase[idx] = *(const float4*)&outst[pix * 28 + sub];
            }
        }
    }
}

// ---------------- fixk: 4 chunks per block + XCD swizzle --------------------
__global__ __launch_bounds__(256, 4)
void fixk(const float* __restrict__ A64p, const float* __restrict__ Ggrp_p,
          const float* __restrict__ Wf32, float* __restrict__ out)
{
    __shared__ float cpart[4][64];
    __shared__ float carry4[4][64];
    __shared__ float part[4][24][8];
    __shared__ float vfix[4][24];
    int tid = threadIdx.x;
    int raw = blockIdx.x;
    int bi = ((raw & 7) << 7) | (raw >> 3);     // XCD swizzle: 1024 blocks
    int b = bi >> 8, quad = bi & 255;
    int ci0 = quad * 4, g = ci0 >> 6, cr0 = ci0 & 63;
    int w = tid >> 6, ln = tid & 63;

    {   // distributed carry prefix to ci0
        float s = 0.f;
        for (int j = w; j < g; j += 4)
            s += Ggrp_p[(size_t)(b * NG + j) * 64 + ln];
        const float* ap = A64p + (size_t)(b * CI + g * 64) * 64 + ln;
        for (int j = w; j < cr0; j += 4) s += ap[j * 64];
        cpart[w][ln] = s;
    }
    __syncthreads();
    if (tid < 64) {                             // extend to 4 per-chunk carries
        float c = cpart[0][tid] + cpart[1][tid] + cpart[2][tid] + cpart[3][tid];
        const float* arow = A64p + (size_t)(b * CI + ci0) * 64 + tid;
        carry4[0][tid] = c;
        c += arow[0];   carry4[1][tid] = c;
        c += arow[64];  carry4[2][tid] = c;
        c += arow[128]; carry4[3][tid] = c;
    }
    __syncthreads();
    if (tid < 192) {                            // 4 chunks x 24 outputs x 8 segs
        int ck = tid >> 3, sg = tid & 7;
        const float* wp = Wf32 + ck * 64 + sg * 8;
#pragma unroll
        for (int k = 0; k < 4; ++k) {
            const float* cp = &carry4[k][sg * 8];
            float vf = 0.f;
#pragma unroll
            for (int d = 0; d < 8; ++d) vf += cp[d] * wp[d];
            part[k][ck][sg] = vf;
        }
    }
    __syncthreads();
    if (tid < 96) {
        int k = tid / 24, ck = tid % 24;
        float vf = 0.f;
#pragma unroll
        for (int j = 0; j < 8; ++j) vf += part[k][ck][j];
        vfix[k][ck] = INVN * vf;
    }
    __syncthreads();
    // RMW: 4 chunks x 384 float4 = 1536, contiguous (chunks consecutive)
    float4* obase = (float4*)(out + ((size_t)b * SS + (size_t)(ci0 * 64) * 3) * 8);
#pragma unroll
    for (int kk = 0; kk < 6; ++kk) {
        int idx = kk * 256 + tid;               // 0..1535
        int k = idx / 384, rem = idx - k * 384;
        int sub = (rem % 6) * 4;
        float4 v = obase[idx];
        v.x += vfix[k][sub];
        v.y += vfix[k][sub + 1];
        v.z += vfix[k][sub + 2];
        v.w += vfix[k][sub + 3];
        obase[idx] = v;
    }
}

// ---------------- host -------------------------------------------------------
extern "C" void kernel_launch(void* const* d_in, const int* in_sizes, int n_in,
                              void* d_out, int out_size, void* d_ws, size_t ws_size,
                              hipStream_t stream)
{
    const int*   ex   = (const int*)d_in[0];
    const float* W0   = (const float*)d_in[1];
    const float* b0   = (const float*)d_in[2];
    const float* Wr   = (const float*)d_in[3];
    const float* br   = (const float*)d_in[4];
    const float* Wfin = (const float*)d_in[5];
    const float* bfin = (const float*)d_in[6];
    float* out = (float*)d_out;

    char* ws = (char*)d_ws;
    size_t off = 0;
    _Float16* Y = (_Float16*)(ws + off); off += (size_t)BB * 3 * SP * 64 * 2;  // 100.7 MB
    float* Ggrp1 = (float*)(ws + off); off += (size_t)BB * NG * 64 * 4;        // contiguous
    float* Ggrp2 = (float*)(ws + off); off += (size_t)BB * NG * 64 * 4;
    float* Ggrp3 = (float*)(ws + off); off += (size_t)BB * NG * 64 * 4;
    float* A64_1 = (float*)(ws + off); off += (size_t)BB * CI * 64 * 4;
    float* A64_2 = (float*)(ws + off); off += (size_t)BB * CI * 64 * 4;
    float* A64_3 = (float*)(ws + off); off += (size_t)BB * CI * 64 * 4;
    int* Hsub = (int*)(ws + off); off += (size_t)BB * CI * 24 * 4;
    int* Hqrt = (int*)(ws + off); off += (size_t)BB * NG * 4 * 24 * 4;
    _Float16* Wt16  = (_Float16*)(ws + off); off += 36864 * 2;
    _Float16* Wf16p = (_Float16*)(ws + off); off += 3072 * 2;
    float* Wf32  = (float*)(ws + off); off += 1536 * 4;
    float* tab32 = (float*)(ws + off); off += 1536 * 4;

    prep<<<256, 256, 0, stream>>>(ex, W0, b0, Wr, Wfin,
                                  Wt16, Wf16p, Wf32, tab32,
                                  Hsub, Hqrt, Ggrp1);
    midA<<<4096, 256, 0, stream>>>(ex, Hsub, Hqrt, tab32,
                                   Wt16, Wr, br, Y, A64_1, Ggrp1);
    midB<<<4096, 256, 0, stream>>>(Y, Y, A64_1, Ggrp1,
                                   Wt16 + 12288, Wr + 12288, br + 192,
                                   A64_2, Ggrp2);
    midC<<<4096, 256, 0, stream>>>(Y, A64_2, Ggrp2,
                                   Wt16 + 24576, Wr + 24576, br + 384,
                                   Wf16p, bfin, out, A64_3, Ggrp3);
    fixk<<<1024, 256, 0, stream>>>(A64_3, Ggrp3, Wf32, out);
}

// Round 15
// 343.992 us; speedup vs baseline: 1.2507x; 1.0290x over previous
//
#include <hip/hip_runtime.h>
#include <stdint.h>

// ---------------------------------------------------------------------------
// R22: R21 champion (354.0 us) + ONE change class: ILP-unrolled prologue
// prefix loops. The A64/Hsub prefix accumulation is a runtime-trip-count
// serial chain (<=16 iters of load->dependent add, ~1-2 loads in flight) on
// the barrier-convoyed critical path (R15: prologue ~10 us/mid of span).
// Fix: 4 independent accumulators (4x-strided unroll + remainder) in
// midA/midB/midC/fixk prefix loops; 2 accumulators in the 64-iter basefold.
// +3-4 regs in a low-pressure phase (die before MFMA) -> no spill risk.
// Float reorder only (R11/R12 empirically kept absmax identical).
// Everything else R21-byte-identical (XCD swizzle, 4-chunk fixk, R14 bodies).
// ---------------------------------------------------------------------------

#define BB 4
#define SP 65536
#define SS 196608
#define CI 1024                 // 64-px chunks per batch
#define NG 16                   // groups per batch (64 chunks each)
#define INVN (1.0f / 196608.0f)

typedef __attribute__((ext_vector_type(8))) _Float16 half8;
typedef __attribute__((ext_vector_type(4))) float    f32x4;

// ---------------- prep: histograms + weight prep + Ggrp zero ----------------
__global__ __launch_bounds__(256)
void prep(const int* __restrict__ ex, const float* __restrict__ W0,
          const float* __restrict__ b0, const float* __restrict__ Wr,
          const float* __restrict__ Wfin,
          _Float16* __restrict__ Wt16, _Float16* __restrict__ Wf16p,
          float* __restrict__ Wf32, float* __restrict__ tab32,
          int* __restrict__ Hsub, int* __restrict__ Hqrt,
          float* __restrict__ Gz)
{
    __shared__ int hist[16][24];
    int tid = threadIdx.x, bi = blockIdx.x;        // 256 blocks
    int b = bi >> 6, g = (bi >> 2) & 15, q = bi & 3;  // quarter-group = 16 chunks
    for (int i = tid; i < 384; i += 256) hist[i / 24][i % 24] = 0;
    __syncthreads();
    for (int it = 0; it < 4; ++it) {
        int pl = it * 256 + tid;                   // 0..1023 within quarter
        const int* ep = ex + ((size_t)b * SP + g * 4096 + q * 1024 + pl) * 3;
        int j = pl >> 6;                           // chunk within quarter
        atomicAdd(&hist[j][ep[0]], 1);
        atomicAdd(&hist[j][8 + ep[1]], 1);
        atomicAdd(&hist[j][16 + ep[2]], 1);
    }
    __syncthreads();
    for (int i = tid; i < 384; i += 256) {
        int j = i / 24, cv = i % 24;
        Hsub[(size_t)(b * CI + g * 64 + q * 16 + j) * 24 + cv] = hist[j][cv];
    }
    if (tid < 24) {
        int s = 0;
        for (int j = 0; j < 16; ++j) s += hist[j][tid];
        Hqrt[((size_t)(b * NG + g) * 4 + q) * 24 + tid] = s;   // non-atomic
    }
    {   // weight prep + Ggrp zeroing (all 256 blocks share)
        int i0 = bi * 256 + tid, nth = 256 * 256;
        for (int idx = i0; idx < 12288; idx += nth)     // Ggrp1..3 zero
            Gz[idx] = 0.f;
        for (int idx = i0; idx < 36864; idx += nth) {   // Wt16[l][c][f][d]
            int d = idx & 63, f = (idx >> 6) & 63, lc = idx >> 12;
            Wt16[idx] = (_Float16)Wr[(size_t)(lc * 64 + d) * 64 + f];
        }
        for (int idx = i0; idx < 3072; idx += nth) {    // Wf16p[c][n16][d]
            int d = idx & 63, n = (idx >> 6) & 15, c = idx >> 10;
            Wf16p[idx] = (n < 8) ? (_Float16)Wfin[(size_t)(c * 64 + d) * 8 + n]
                                 : (_Float16)0.f;
        }
        for (int idx = i0; idx < 1536; idx += nth) {    // Wf32[ck][d]
            int d = idx & 63, ck = idx >> 6;
            Wf32[idx] = Wfin[(size_t)((ck >> 3) * 64 + d) * 8 + (ck & 7)];
        }
        for (int idx = i0; idx < 1536; idx += nth) {    // tab32[cv][f]
            int f = idx & 63, v = (idx >> 6) & 7, c = idx >> 9;
            float xv = v * 0.25f - 1.0f;
            tab32[idx] = fmaxf(W0[c * 64 + f] * xv + b0[c * 64 + f], 0.f);
        }
    }
}

// ---------------- midA: R14 body + XCD swizzle + ILP prologue ---------------
__global__ __launch_bounds__(256, 4)
void midA(const int* __restrict__ ex,
          const int* __restrict__ Hsub, const int* __restrict__ Hqrt,
          const float* __restrict__ tab32,
          const _Float16* __restrict__ W16, const float* __restrict__ Wd32,
          const float* __restrict__ bias, _Float16* __restrict__ Y,
          float* __restrict__ A64, float* __restrict__ Ggrp)
{
    __shared__ float stab[1536];
    __shared__ __align__(16) _Float16 bounce3[3][64 * 72];
    __shared__ float segwt[3][4][64];
    __shared__ float basearr[192];
    __shared__ float hpart[4][24];
    __shared__ float carry[64];

    int tid = threadIdx.x;
    int raw = blockIdx.x;
    int bi = ((raw & 7) << 9) | (raw >> 3);    // XCD swizzle: 4096 blocks
    int b = bi >> 10, ci = bi & 1023, g = ci >> 6, cr = ci & 63;
    int w = tid >> 6, ln = tid & 63, lm = ln & 15, lq = ln >> 4;
    int P0 = ci * 64;

    for (int i = tid; i < 1536; i += 256) stab[i] = tab32[i];
    if (ln < 24) {                             // distributed hist prefix (ILP)
        float s = 0.f;
        for (int j = w; j < g; j += 4) {
            const int* hq = Hqrt + ((size_t)(b * NG + j) * 4) * 24 + ln;
            s += (float)(hq[0] + hq[24] + hq[48] + hq[72]);
        }
        const int* hp = Hsub + (size_t)(b * CI + g * 64) * 24 + ln;
        float t0 = 0.f, t1 = 0.f, t2 = 0.f, t3 = 0.f;
        int j = w;
        for (; j + 12 < cr; j += 16) {
            t0 += (float)hp[j * 24];
            t1 += (float)hp[(j + 4) * 24];
            t2 += (float)hp[(j + 8) * 24];
            t3 += (float)hp[(j + 12) * 24];
        }
        for (; j < cr; j += 4) t0 += (float)hp[j * 24];
        hpart[w][ln] = s + ((t0 + t1) + (t2 + t3));
    }
    __syncthreads();                           // B1: stab + hpart

    // layer-0 local values: thread (f=ln, seg=w) scans 16 px
    float y0[3][16];
    {
#pragma unroll
        for (int p = 0; p < 16; ++p) {
            const int* ep = ex + ((size_t)b * SP + P0 + w * 16 + p) * 3;
            y0[0][p] = stab[ep[0] * 64 + ln];
            y0[1][p] = stab[(8 + ep[1]) * 64 + ln];
            y0[2][p] = stab[(16 + ep[2]) * 64 + ln];
        }
#pragma unroll
        for (int c = 0; c < 3; ++c)
#pragma unroll
            for (int p = 1; p < 16; ++p) y0[c][p] += y0[c][p - 1];
#pragma unroll
        for (int c = 0; c < 3; ++c) segwt[c][w][ln] = y0[c][15];
    }
    if (tid < 64) {                            // layer-0 carry from hist
        float c0 = 0.f;
#pragma unroll
        for (int cv = 0; cv < 24; ++cv) {
            float cnt = hpart[0][cv] + hpart[1][cv] + hpart[2][cv] + hpart[3][cv];
            c0 += cnt * stab[cv * 64 + tid];
        }
        carry[tid] = c0;
    }
    __syncthreads();                           // B2: segwt + carry

    {   // combine channels -> bounce (layer-0 chunk-local flattened cumsum)
        float off0[3];
#pragma unroll
        for (int c = 0; c < 3; ++c) {
            float o = 0.f;
            for (int w2 = 0; w2 < w; ++w2) o += segwt[c][w2][ln];
            off0[c] = o;
        }
#pragma unroll
        for (int p = 0; p < 16; ++p) {
            float S0 = y0[0][p] + off0[0], S1 = y0[1][p] + off0[1], S2 = y0[2][p] + off0[2];
            float P1 = p ? y0[1][p - 1] + off0[1] : off0[1];
            float P2 = p ? y0[2][p - 1] + off0[2] : off0[2];
            int row = w * 16 + p;
            bounce3[0][row * 72 + ln] = (_Float16)(S0 + P1 + P2);
            bounce3[1][row * 72 + ln] = (_Float16)(S0 + S1 + P2);
            bounce3[2][row * 72 + ln] = (_Float16)(S0 + S1 + S2);
        }
    }
    if (tid < 192) {                           // basefold for dense1 (2 accs)
        int c = tid >> 6, f = tid & 63;
        const float* wp = Wd32 + (size_t)(c * 64) * 64 + f;
        float a0 = 0.f, a1 = 0.f;
#pragma unroll
        for (int d = 0; d < 64; d += 2) {
            a0 += carry[d] * wp[d * 64];
            a1 += carry[d + 1] * wp[(d + 1) * 64];
        }
        basearr[tid] = bias[tid] + INVN * (a0 + a1);
    }
    __syncthreads();                           // B3: bounce + basearr

    // dense1 MFMA
    f32x4 acc[3][4];
#pragma unroll
    for (int c = 0; c < 3; ++c) {
        const half8* bb = (const half8*)&bounce3[c][0];
        half8 a0 = bb[(w * 16 + lm) * 9 + lq];
        half8 a1 = bb[(w * 16 + lm) * 9 + 4 + lq];
#pragma unroll
        for (int nt = 0; nt < 4; ++nt) {
            const half8* bp = (const half8*)(W16 + (size_t)(c * 64 + nt * 16 + lm) * 64);
            f32x4 t = {0.f, 0.f, 0.f, 0.f};
            t = __builtin_amdgcn_mfma_f32_16x16x32_f16(a0, bp[lq],     t, 0, 0, 0);
            t = __builtin_amdgcn_mfma_f32_16x16x32_f16(a1, bp[4 + lq], t, 0, 0, 0);
            acc[c][nt] = t;
        }
    }

    // relu + scan + shuffle
    float s[3][4][4], wexcl[3][4];
#pragma unroll
    for (int c = 0; c < 3; ++c)
#pragma unroll
        for (int nt = 0; nt < 4; ++nt) {
            float base = basearr[c * 64 + nt * 16 + lm];
            float run = 0.f;
#pragma unroll
            for (int r = 0; r < 4; ++r) {
                float yv = fmaxf(base + INVN * acc[c][nt][r], 0.f);
                run += yv; s[c][nt][r] = run;
            }
            float v = run;
            float t1 = __shfl_up(v, 16); if (lq >= 1) v += t1;
            float t2 = __shfl_up(v, 32); if (lq >= 2) v += t2;
            wexcl[c][nt] = v - run;
            if (lq == 3) segwt[c][w][nt * 16 + lm] = v;   // wave totals
        }
    __syncthreads();                           // B4: wave tops

    {
        float off[3][4], tot[3][4];
#pragma unroll
        for (int c = 0; c < 3; ++c)
#pragma unroll
            for (int nt = 0; nt < 4; ++nt) {
                float o = wexcl[c][nt], ts = 0.f;
#pragma unroll
                for (int w2 = 0; w2 < 4; ++w2) {
                    float wv = segwt[c][w2][nt * 16 + lm];
                    ts += wv;
                    if (w2 < w) o += wv;
                }
                off[c][nt] = o; tot[c][nt] = ts;
            }
        if (w == 0 && lq == 0)
#pragma unroll
            for (int nt = 0; nt < 4; ++nt) {
                float t3 = tot[0][nt] + tot[1][nt] + tot[2][nt];
                A64[(size_t)(b * CI + ci) * 64 + nt * 16 + lm] = t3;
                atomicAdd(&Ggrp[(size_t)(b * NG + g) * 64 + nt * 16 + lm], t3);
            }
#pragma unroll
        for (int nt = 0; nt < 4; ++nt)
#pragma unroll
            for (int r = 0; r < 4; ++r) {
                float S0 = off[0][nt] + s[0][nt][r];
                float S1 = off[1][nt] + s[1][nt][r];
                float S2 = off[2][nt] + s[2][nt][r];
                float P1 = off[1][nt] + (r ? s[1][nt][r - 1] : 0.f);
                float P2 = off[2][nt] + (r ? s[2][nt][r - 1] : 0.f);
                int row = w * 16 + lq * 4 + r;
                bounce3[0][row * 72 + nt * 16 + lm] = (_Float16)(S0 + P1 + P2);
                bounce3[1][row * 72 + nt * 16 + lm] = (_Float16)(S0 + S1 + P2);
                bounce3[2][row * 72 + nt * 16 + lm] = (_Float16)(S0 + S1 + S2);
            }
    }
    __syncthreads();                           // B5: store staging
#pragma unroll
    for (int q = 0; q < 6; ++q) {
        int idx = q * 256 + tid;
        int c = idx >> 9, rem = idx & 511;
        int pix = rem >> 3, f8 = rem & 7;
        half8 v = *(const half8*)&bounce3[c][pix * 72 + f8 * 8];
        ((half8*)(Y + ((size_t)(b * 3 + c) * SP + P0 + pix) * 64))[f8] = v;
    }
}

// ---------------- midB: R14 body + XCD swizzle + ILP prologue ---------------
__global__ __launch_bounds__(256, 4)
void midB(const _Float16* Yin, _Float16* Yout,
          const float* __restrict__ A64p, const float* __restrict__ Ggrp_p,
          const _Float16* __restrict__ W16, const float* __restrict__ Wd32,
          const float* __restrict__ bias,
          float* __restrict__ A64, float* __restrict__ Ggrp)
{
    __shared__ __align__(16) _Float16 bounce3[3][64 * 72];
    __shared__ float wtop[3][4][64];
    __shared__ float basearr[192];
    __shared__ float cpart[4][64];
    __shared__ float carry[64];

    int tid = threadIdx.x;
    int raw = blockIdx.x;
    int bi = ((raw & 7) << 9) | (raw >> 3);    // XCD swizzle: 4096 blocks
    int b = bi >> 10, ci = bi & 1023, g = ci >> 6, cr = ci & 63;
    int w = tid >> 6, ln = tid & 63, lm = ln & 15, lq = ln >> 4;
    int P0 = ci * 64;

    // A-frags first (latency hidden behind prologue)
    half8 af0[3], af1[3];
#pragma unroll
    for (int c = 0; c < 3; ++c) {
        const half8* ap = (const half8*)(Yin + ((size_t)(b * 3 + c) * SP + P0 + w * 16 + lm) * 64);
        af0[c] = ap[lq]; af1[c] = ap[4 + lq];
    }
    {   // distributed carry prefix (ILP: 4 accumulators on the long loop)
        float s = 0.f;
        for (int j = w; j < g; j += 4)
            s += Ggrp_p[(size_t)(b * NG + j) * 64 + ln];
        const float* ap = A64p + (size_t)(b * CI + g * 64) * 64 + ln;
        float t0 = 0.f, t1 = 0.f, t2 = 0.f, t3 = 0.f;
        int j = w;
        for (; j + 12 < cr; j += 16) {
            t0 += ap[j * 64];
            t1 += ap[(j + 4) * 64];
            t2 += ap[(j + 8) * 64];
            t3 += ap[(j + 12) * 64];
        }
        for (; j < cr; j += 4) t0 += ap[j * 64];
        cpart[w][ln] = s + ((t0 + t1) + (t2 + t3));
    }
    __syncthreads();                           // B1
    if (tid < 64)
        carry[tid] = cpart[0][tid] + cpart[1][tid] + cpart[2][tid] + cpart[3][tid];
    __syncthreads();                           // B2
    if (tid < 192) {                           // basefold (2 accs)
        int c = tid >> 6, f = tid & 63;
        const float* wp = Wd32 + (size_t)(c * 64) * 64 + f;
        float a0 = 0.f, a1 = 0.f;
#pragma unroll
        for (int d = 0; d < 64; d += 2) {
            a0 += carry[d] * wp[d * 64];
            a1 += carry[d + 1] * wp[(d + 1) * 64];
        }
        basearr[tid] = bias[tid] + INVN * (a0 + a1);
    }
    __syncthreads();                           // B3

    f32x4 acc[3][4];
#pragma unroll
    for (int c = 0; c < 3; ++c)
#pragma unroll
        for (int nt = 0; nt < 4; ++nt) {
            const half8* bp = (const half8*)(W16 + (size_t)(c * 64 + nt * 16 + lm) * 64);
            f32x4 t = {0.f, 0.f, 0.f, 0.f};
            t = __builtin_amdgcn_mfma_f32_16x16x32_f16(af0[c], bp[lq],     t, 0, 0, 0);
            t = __builtin_amdgcn_mfma_f32_16x16x32_f16(af1[c], bp[4 + lq], t, 0, 0, 0);
            acc[c][nt] = t;
        }

    float s[3][4][4], wexcl[3][4];
#pragma unroll
    for (int c = 0; c < 3; ++c)
#pragma unroll
        for (int nt = 0; nt < 4; ++nt) {
            float base = basearr[c * 64 + nt * 16 + lm];
            float run = 0.f;
#pragma unroll
            for (int r = 0; r < 4; ++r) {
                float yv = fmaxf(base + INVN * acc[c][nt][r], 0.f);
                run += yv; s[c][nt][r] = run;
            }
            float v = run;
            float t1 = __shfl_up(v, 16); if (lq >= 1) v += t1;
            float t2 = __shfl_up(v, 32); if (lq >= 2) v += t2;
            wexcl[c][nt] = v - run;
            if (lq == 3) wtop[c][w][nt * 16 + lm] = v;
        }
    __syncthreads();                           // B4

    {
        float off[3][4], tot[3][4];
#pragma unroll
        for (int c = 0; c < 3; ++c)
#pragma unroll
            for (int nt = 0; nt < 4; ++nt) {
                float o = wexcl[c][nt], ts = 0.f;
#pragma unroll
                for (int w2 = 0; w2 < 4; ++w2) {
                    float wv = wtop[c][w2][nt * 16 + lm];
                    ts += wv;
                    if (w2 < w) o += wv;
                }
                off[c][nt] = o; tot[c][nt] = ts;
            }
        if (w == 0 && lq == 0)
#pragma unroll
            for (int nt = 0; nt < 4; ++nt) {
                float t3 = tot[0][nt] + tot[1][nt] + tot[2][nt];
                A64[(size_t)(b * CI + ci) * 64 + nt * 16 + lm] = t3;
                atomicAdd(&Ggrp[(size_t)(b * NG + g) * 64 + nt * 16 + lm], t3);
            }
#pragma unroll
        for (int nt = 0; nt < 4; ++nt)
#pragma unroll
            for (int r = 0; r < 4; ++r) {
                float S0 = off[0][nt] + s[0][nt][r];
                float S1 = off[1][nt] + s[1][nt][r];
                float S2 = off[2][nt] + s[2][nt][r];
                float P1 = off[1][nt] + (r ? s[1][nt][r - 1] : 0.f);
                float P2 = off[2][nt] + (r ? s[2][nt][r - 1] : 0.f);
                int row = w * 16 + lq * 4 + r;
                bounce3[0][row * 72 + nt * 16 + lm] = (_Float16)(S0 + P1 + P2);
                bounce3[1][row * 72 + nt * 16 + lm] = (_Float16)(S0 + S1 + P2);
                bounce3[2][row * 72 + nt * 16 + lm] = (_Float16)(S0 + S1 + S2);
            }
    }
    __syncthreads();                           // B5
#pragma unroll
    for (int q = 0; q < 6; ++q) {
        int idx = q * 256 + tid;
        int c = idx >> 9, rem = idx & 511;
        int pix = rem >> 3, f8 = rem & 7;
        half8 v = *(const half8*)&bounce3[c][pix * 72 + f8 * 8];
        ((half8*)(Yout + ((size_t)(b * 3 + c) * SP + P0 + pix) * 64))[f8] = v;
    }
}

// ---------------- midC: R14 body + XCD swizzle + ILP prologue ---------------
__global__ __launch_bounds__(256, 4)
void midC(const _Float16* __restrict__ Yin,
          const float* __restrict__ A64p, const float* __restrict__ Ggrp_p,
          const _Float16* __restrict__ W16, const float* __restrict__ Wd32,
          const float* __restrict__ bias,
          const _Float16* __restrict__ Wf16p, const float* __restrict__ bfin,
          float* __restrict__ out, float* __restrict__ A64, float* __restrict__ Ggrp)
{
    __shared__ __align__(16) _Float16 bounce3[3][64 * 72];
    __shared__ float wtop[3][4][64];
    __shared__ float basearr[192];
    __shared__ float cpart[4][64];
    __shared__ float carry[64];
    __shared__ __align__(16) float outst[64 * 28];

    int tid = threadIdx.x;
    int raw = blockIdx.x;
    int bi = ((raw & 7) << 9) | (raw >> 3);    // XCD swizzle: 4096 blocks
    int b = bi >> 10, ci = bi & 1023, g = ci >> 6, cr = ci & 63;
    int w = tid >> 6, ln = tid & 63, lm = ln & 15, lq = ln >> 4;
    int P0 = ci * 64;

    half8 af0[3], af1[3];
#pragma unroll
    for (int c = 0; c < 3; ++c) {
        const half8* ap = (const half8*)(Yin + ((size_t)(b * 3 + c) * SP + P0 + w * 16 + lm) * 64);
        af0[c] = ap[lq]; af1[c] = ap[4 + lq];
    }
    {   // distributed carry prefix (ILP)
        float s = 0.f;
        for (int j = w; j < g; j += 4)
            s += Ggrp_p[(size_t)(b * NG + j) * 64 + ln];
        const float* ap = A64p + (size_t)(b * CI + g * 64) * 64 + ln;
        float t0 = 0.f, t1 = 0.f, t2 = 0.f, t3 = 0.f;
        int j = w;
        for (; j + 12 < cr; j += 16) {
            t0 += ap[j * 64];
            t1 += ap[(j + 4) * 64];
            t2 += ap[(j + 8) * 64];
            t3 += ap[(j + 12) * 64];
        }
        for (; j < cr; j += 4) t0 += ap[j * 64];
        cpart[w][ln] = s + ((t0 + t1) + (t2 + t3));
    }
    __syncthreads();                           // B1
    if (tid < 64)
        carry[tid] = cpart[0][tid] + cpart[1][tid] + cpart[2][tid] + cpart[3][tid];
    __syncthreads();                           // B2
    if (tid < 192) {                           // basefold (2 accs)
        int c = tid >> 6, f = tid & 63;
        const float* wp = Wd32 + (size_t)(c * 64) * 64 + f;
        float a0 = 0.f, a1 = 0.f;
#pragma unroll
        for (int d = 0; d < 64; d += 2) {
            a0 += carry[d] * wp[d * 64];
            a1 += carry[d + 1] * wp[(d + 1) * 64];
        }
        basearr[tid] = bias[tid] + INVN * (a0 + a1);
    }
    __syncthreads();                           // B3

    f32x4 acc[3][4];
#pragma unroll
    for (int c = 0; c < 3; ++c)
#pragma unroll
        for (int nt = 0; nt < 4; ++nt) {
            const half8* bp = (const half8*)(W16 + (size_t)(c * 64 + nt * 16 + lm) * 64);
            f32x4 t = {0.f, 0.f, 0.f, 0.f};
            t = __builtin_amdgcn_mfma_f32_16x16x32_f16(af0[c], bp[lq],     t, 0, 0, 0);
            t = __builtin_amdgcn_mfma_f32_16x16x32_f16(af1[c], bp[4 + lq], t, 0, 0, 0);
            acc[c][nt] = t;
        }

    float s[3][4][4], wexcl[3][4];
#pragma unroll
    for (int c = 0; c < 3; ++c)
#pragma unroll
        for (int nt = 0; nt < 4; ++nt) {
            float base = basearr[c * 64 + nt * 16 + lm];
            float run = 0.f;
#pragma unroll
            for (int r = 0; r < 4; ++r) {
                float yv = fmaxf(base + INVN * acc[c][nt][r], 0.f);
                run += yv; s[c][nt][r] = run;
            }
            float v = run;
            float t1 = __shfl_up(v, 16); if (lq >= 1) v += t1;
            float t2 = __shfl_up(v, 32); if (lq >= 2) v += t2;
            wexcl[c][nt] = v - run;
            if (lq == 3) wtop[c][w][nt * 16 + lm] = v;
        }
    __syncthreads();                           // B4

    {
        float off[3][4], tot[3][4];
#pragma unroll
        for (int c = 0; c < 3; ++c)
#pragma unroll
            for (int nt = 0; nt < 4; ++nt) {
                float o = wexcl[c][nt], ts = 0.f;
#pragma unroll
                for (int w2 = 0; w2 < 4; ++w2) {
                    float wv = wtop[c][w2][nt * 16 + lm];
                    ts += wv;
                    if (w2 < w) o += wv;
                }
                off[c][nt] = o; tot[c][nt] = ts;
            }
        if (w == 0 && lq == 0)
#pragma unroll
            for (int nt = 0; nt < 4; ++nt) {
                float t3 = tot[0][nt] + tot[1][nt] + tot[2][nt];
                A64[(size_t)(b * CI + ci) * 64 + nt * 16 + lm] = t3;
                atomicAdd(&Ggrp[(size_t)(b * NG + g) * 64 + nt * 16 + lm], t3);
            }
#pragma unroll
        for (int nt = 0; nt < 4; ++nt)
#pragma unroll
            for (int r = 0; r < 4; ++r) {
                float S0 = off[0][nt] + s[0][nt][r];
                float S1 = off[1][nt] + s[1][nt][r];
                float S2 = off[2][nt] + s[2][nt][r];
                float P1 = off[1][nt] + (r ? s[1][nt][r - 1] : 0.f);
                float P2 = off[2][nt] + (r ? s[2][nt][r - 1] : 0.f);
                int row = w * 16 + lq * 4 + r;
                bounce3[0][row * 72 + nt * 16 + lm] = (_Float16)(S0 + P1 + P2);
                bounce3[1][row * 72 + nt * 16 + lm] = (_Float16)(S0 + S1 + P2);
                bounce3[2][row * 72 + nt * 16 + lm] = (_Float16)(S0 + S1 + S2);
            }
    }
    __syncthreads();                           // B5: layer-3 local staged

    // final dense via padded-Wf MFMA (n=16: 8 logits + 8 zero)
#pragma unroll
    for (int c = 0; c < 3; ++c) {
        const half8* bb = (const half8*)&bounce3[c][0];
        half8 fa0 = bb[(w * 16 + lm) * 9 + lq];
        half8 fa1 = bb[(w * 16 + lm) * 9 + 4 + lq];
        const half8* fb = (const half8*)(Wf16p + (size_t)(c * 16 + lm) * 64);
        f32x4 t = {0.f, 0.f, 0.f, 0.f};
        t = __builtin_amdgcn_mfma_f32_16x16x32_f16(fa0, fb[lq],     t, 0, 0, 0);
        t = __builtin_amdgcn_mfma_f32_16x16x32_f16(fa1, fb[4 + lq], t, 0, 0, 0);
        if (lm < 8) {
            float bz = bfin[c * 8 + lm];
#pragma unroll
            for (int r = 0; r < 4; ++r)
                outst[(w * 16 + lq * 4 + r) * 28 + c * 8 + lm] = bz + INVN * t[r];
        }
    }
    __syncthreads();                           // B6
    {   // 64 px x 24 floats = 384 float4
        float4* obase = (float4*)(out + ((size_t)b * SS + (size_t)P0 * 3) * 8);
#pragma unroll
        for (int k = 0; k < 2; ++k) {
            int idx = k * 256 + tid;
            if (idx < 384) {
                int pix = idx / 6, sub = (idx % 6) * 4;
                obase[idx] = *(const float4*)&outst[pix * 28 + sub];
            }
        }
    }
}

// ---------------- fixk: 4 chunks per block + XCD swizzle + ILP --------------
__global__ __launch_bounds__(256, 4)
void fixk(const float* __restrict__ A64p, const float* __restrict__ Ggrp_p,
          const float* __restrict__ Wf32, float* __restrict__ out)
{
    __shared__ float cpart[4][64];
    __shared__ float carry4[4][64];
    __shared__ float part[4][24][8];
    __shared__ float vfix[4][24];
    int tid = threadIdx.x;
    int raw = blockIdx.x;
    int bi = ((raw & 7) << 7) | (raw >> 3);     // XCD swizzle: 1024 blocks
    int b = bi >> 8, quad = bi & 255;
    int ci0 = quad * 4, g = ci0 >> 6, cr0 = ci0 & 63;
    int w = tid >> 6, ln = tid & 63;

    {   // distributed carry prefix to ci0 (ILP)
        float s = 0.f;
        for (int j = w; j < g; j += 4)
            s += Ggrp_p[(size_t)(b * NG + j) * 64 + ln];
        const float* ap = A64p + (size_t)(b * CI + g * 64) * 64 + ln;
        float t0 = 0.f, t1 = 0.f, t2 = 0.f, t3 = 0.f;
        int j = w;
        for (; j + 12 < cr0; j += 16) {
            t0 += ap[j * 64];
            t1 += ap[(j + 4) * 64];
            t2 += ap[(j + 8) * 64];
            t3 += ap[(j + 12) * 64];
        }
        for (; j < cr0; j += 4) t0 += ap[j * 64];
        cpart[w][ln] = s + ((t0 + t1) + (t2 + t3));
    }
    __syncthreads();
    if (tid < 64) {                             // extend to 4 per-chunk carries
        float c = cpart[0][tid] + cpart[1][tid] + cpart[2][tid] + cpart[3][tid];
        const float* arow = A64p + (size_t)(b * CI + ci0) * 64 + tid;
        carry4[0][tid] = c;
        c += arow[0];   carry4[1][tid] = c;
        c += arow[64];  carry4[2][tid] = c;
        c += arow[128]; carry4[3][tid] = c;
    }
    __syncthreads();
    if (tid < 192) {                            // 4 chunks x 24 outputs x 8 segs
        int ck = tid >> 3, sg = tid & 7;
        const float* wp = Wf32 + ck * 64 + sg * 8;
#pragma unroll
        for (int k = 0; k < 4; ++k) {
            const float* cp = &carry4[k][sg * 8];
            float vf = 0.f;
#pragma unroll
            for (int d = 0; d < 8; ++d) vf += cp[d] * wp[d];
            part[k][ck][sg] = vf;
        }
    }
    __syncthreads();
    if (tid < 96) {
        int k = tid / 24, ck = tid % 24;
        float vf = 0.f;
#pragma unroll
        for (int j = 0; j < 8; ++j) vf += part[k][ck][j];
        vfix[k][ck] = INVN * vf;
    }
    __syncthreads();
    // RMW: 4 chunks x 384 float4 = 1536, contiguous (chunks consecutive)
    float4* obase = (float4*)(out + ((size_t)b * SS + (size_t)(ci0 * 64) * 3) * 8);
#pragma unroll
    for (int kk = 0; kk < 6; ++kk) {
        int idx = kk * 256 + tid;               // 0..1535
        int k = idx / 384, rem = idx - k * 384;
        int sub = (rem % 6) * 4;
        float4 v = obase[idx];
        v.x += vfix[k][sub];
        v.y += vfix[k][sub + 1];
        v.z += vfix[k][sub + 2];
        v.w += vfix[k][sub + 3];
        obase[idx] = v;
    }
}

// ---------------- host -------------------------------------------------------
extern "C" void kernel_launch(void* const* d_in, const int* in_sizes, int n_in,
                              void* d_out, int out_size, void* d_ws, size_t ws_size,
                              hipStream_t stream)
{
    const int*   ex   = (const int*)d_in[0];
    const float* W0   = (const float*)d_in[1];
    const float* b0   = (const float*)d_in[2];
    const float* Wr   = (const float*)d_in[3];
    const float* br   = (const float*)d_in[4];
    const float* Wfin = (const float*)d_in[5];
    const float* bfin = (const float*)d_in[6];
    float* out = (float*)d_out;

    char* ws = (char*)d_ws;
    size_t off = 0;
    _Float16* Y = (_Float16*)(ws + off); off += (size_t)BB * 3 * SP * 64 * 2;  // 100.7 MB
    float* Ggrp1 = (float*)(ws + off); off += (size_t)BB * NG * 64 * 4;        // contiguous
    float* Ggrp2 = (float*)(ws + off); off += (size_t)BB * NG * 64 * 4;
    float* Ggrp3 = (float*)(ws + off); off += (size_t)BB * NG * 64 * 4;
    float* A64_1 = (float*)(ws + off); off += (size_t)BB * CI * 64 * 4;
    float* A64_2 = (float*)(ws + off); off += (size_t)BB * CI * 64 * 4;
    float* A64_3 = (float*)(ws + off); off += (size_t)BB * CI * 64 * 4;
    int* Hsub = (int*)(ws + off); off += (size_t)BB * CI * 24 * 4;
    int* Hqrt = (int*)(ws + off); off += (size_t)BB * NG * 4 * 24 * 4;
    _Float16* Wt16  = (_Float16*)(ws + off); off += 36864 * 2;
    _Float16* Wf16p = (_Float16*)(ws + off); off += 3072 * 2;
    float* Wf32  = (float*)(ws + off); off += 1536 * 4;
    float* tab32 = (float*)(ws + off); off += 1536 * 4;

    prep<<<256, 256, 0, stream>>>(ex, W0, b0, Wr, Wfin,
                                  Wt16, Wf16p, Wf32, tab32,
                                  Hsub, Hqrt, Ggrp1);
    midA<<<4096, 256, 0, stream>>>(ex, Hsub, Hqrt, tab32,
                                   Wt16, Wr, br, Y, A64_1, Ggrp1);
    midB<<<4096, 256, 0, stream>>>(Y, Y, A64_1, Ggrp1,
                                   Wt16 + 12288, Wr + 12288, br + 192,
                                   A64_2, Ggrp2);
    midC<<<4096, 256, 0, stream>>>(Y, A64_2, Ggrp2,
                                   Wt16 + 24576, Wr + 24576, br + 384,
                                   Wf16p, bfin, out, A64_3, Ggrp3);
    fixk<<<1024, 256, 0, stream>>>(A64_3, Ggrp3, Wf32, out);
}